// Round 2
// baseline (6417.661 us; speedup 1.0000x reference)
//
#include <hip/hip_runtime.h>
#include <hip/hip_bf16.h>
#include <math.h>

#define DIM   384
#define HEADS 8
#define HD    48      // per-head channels
#define HH    96
#define WW    96
#define NPIX  9216    // 96*96
#define OC3   1152    // 3*DIM
#define NS    8       // K-splits for gram

// ---------------- K1/K7: 1x1 conv = GEMM  Y[o,hw] = sum_c W[o,c] * X[c,hw]
// grid: (NPIX/1024, OC/32), block 256. Each thread: 4 hw (float4) x 32 o.
__global__ void conv1x1_kernel(const float* __restrict__ Wm, const float* __restrict__ X,
                               float* __restrict__ Y) {
    __shared__ float ws[32][DIM];
    const int tid = threadIdx.x;
    const int o0 = blockIdx.y * 32;
    for (int i = tid; i < 32 * DIM; i += 256)
        ws[i / DIM][i % DIM] = Wm[(o0 + i / DIM) * DIM + (i % DIM)];
    __syncthreads();
    const int hw0 = blockIdx.x * 1024 + tid * 4;
    float acc[32][4];
#pragma unroll
    for (int j = 0; j < 32; ++j)
        for (int q = 0; q < 4; ++q) acc[j][q] = 0.f;
    for (int c = 0; c < DIM; ++c) {
        const float4 xv = *reinterpret_cast<const float4*>(&X[c * NPIX + hw0]);
#pragma unroll
        for (int j = 0; j < 32; ++j) {
            const float wv = ws[j][c];
            acc[j][0] += wv * xv.x; acc[j][1] += wv * xv.y;
            acc[j][2] += wv * xv.z; acc[j][3] += wv * xv.w;
        }
    }
#pragma unroll
    for (int j = 0; j < 32; ++j)
        *reinterpret_cast<float4*>(&Y[(o0 + j) * NPIX + hw0]) =
            make_float4(acc[j][0], acc[j][1], acc[j][2], acc[j][3]);
}

// ---------------- K2: depthwise 3x3, pad=1. One thread per output element.
__global__ void dwconv_kernel(const float* __restrict__ In, const float* __restrict__ Wd,
                              float* __restrict__ Out) {
    const int idx = blockIdx.x * 256 + threadIdx.x;   // over OC3*NPIX
    const int ch = idx / NPIX;
    const int p  = idx % NPIX;
    const int y = p / WW, x = p % WW;
    const float* wp = &Wd[ch * 9];
    const float* ip = &In[ch * NPIX];
    float acc = 0.f;
#pragma unroll
    for (int dy = -1; dy <= 1; ++dy) {
        const int yy = y + dy;
        if (yy < 0 || yy >= HH) continue;
#pragma unroll
        for (int dx = -1; dx <= 1; ++dx) {
            const int xx = x + dx;
            if (xx < 0 || xx >= WW) continue;
            acc += wp[(dy + 1) * 3 + (dx + 1)] * ip[yy * WW + xx];
        }
    }
    Out[idx] = acc;
}

// ---------------- K3: 1/max(||row||,eps) for q (rows 0..383) and k (rows 384..767)
__global__ void norm_kernel(const float* __restrict__ QK, float* __restrict__ F) {
    const int row = blockIdx.x;            // [0,768)
    const float* src = QK + (size_t)row * NPIX;
    const int tid = threadIdx.x;
    float s = 0.f;
    for (int i = tid; i < NPIX / 4; i += 256) {
        const float4 v = reinterpret_cast<const float4*>(src)[i];
        s += v.x * v.x + v.y * v.y + v.z * v.z + v.w * v.w;
    }
    for (int off = 32; off; off >>= 1) s += __shfl_down(s, off);
    __shared__ float red[4];
    if ((tid & 63) == 0) red[tid >> 6] = s;
    __syncthreads();
    if (tid == 0) {
        const float t = red[0] + red[1] + red[2] + red[3];
        F[row] = 1.f / fmaxf(sqrtf(t), 1e-12f);
    }
}

// ---------------- K4: partial gram  P[h,s,c,d] = sum_{n in chunk s} q[c,n]*k[d,n]
// grid: (NS, HEADS), block 256; thread computes 3x3 (c,d) tile.
__global__ void gram_kernel(const float* __restrict__ QK, float* __restrict__ P) {
    const int h = blockIdx.y, s = blockIdx.x;
    const int n0 = s * (NPIX / NS);
    const float* q = QK + (size_t)(h * HD) * NPIX;
    const float* k = QK + (size_t)(DIM + h * HD) * NPIX;
    __shared__ float qs[HD][132];
    __shared__ float ks[HD][132];
    const int tid = threadIdx.x;
    const int c0 = (tid >> 4) * 3, d0 = (tid & 15) * 3;
    float acc[3][3] = {};
    for (int nb = 0; nb < NPIX / NS; nb += 128) {
        __syncthreads();
        for (int i = tid; i < HD * 32; i += 256) {
            const int r = i / 32, cc = (i % 32) * 4;
            *reinterpret_cast<float4*>(&qs[r][cc]) =
                *reinterpret_cast<const float4*>(&q[(size_t)r * NPIX + n0 + nb + cc]);
            *reinterpret_cast<float4*>(&ks[r][cc]) =
                *reinterpret_cast<const float4*>(&k[(size_t)r * NPIX + n0 + nb + cc]);
        }
        __syncthreads();
        for (int n = 0; n < 128; ++n) {
            float qv[3], kv[3];
#pragma unroll
            for (int i = 0; i < 3; ++i) { qv[i] = qs[c0 + i][n]; kv[i] = ks[d0 + i][n]; }
#pragma unroll
            for (int i = 0; i < 3; ++i)
#pragma unroll
                for (int j = 0; j < 3; ++j) acc[i][j] += qv[i] * kv[j];
        }
    }
#pragma unroll
    for (int i = 0; i < 3; ++i)
#pragma unroll
        for (int j = 0; j < 3; ++j)
            P[((size_t)(h * NS + s) * HD + c0 + i) * HD + d0 + j] = acc[i][j];
}

// ---------------- K5: reduce partials, apply norms+temperature, softmax over d
// grid: HEADS*HD, block 64 (one wave); lane d handles attn[h,c,d]
__global__ void softmax_kernel(const float* __restrict__ P, const float* __restrict__ F,
                               const float* __restrict__ temp, float* __restrict__ A) {
    const int h = blockIdx.x / HD, c = blockIdx.x % HD;
    const int d = threadIdx.x;
    float val = 0.f, v = -INFINITY;
    if (d < HD) {
        float sum = 0.f;
        for (int s = 0; s < NS; ++s) sum += P[((size_t)(h * NS + s) * HD + c) * HD + d];
        val = sum * F[h * HD + c] * F[DIM + h * HD + d] * temp[h];
        v = val;
    }
    float m = v;
    for (int off = 32; off; off >>= 1) m = fmaxf(m, __shfl_xor(m, off));
    const float e = (d < HD) ? expf(val - m) : 0.f;
    float se = e;
    for (int off = 32; off; off >>= 1) se += __shfl_xor(se, off);
    if (d < HD) A[(size_t)(h * HD + c) * HD + d] = e / se;
}

// ---------------- K6: out[c,hw] = sum_d attn[c,d] * v[d,hw]  per head
// grid: (NPIX/256, HEADS), block 256; one hw per thread, 48 accumulators
__global__ void av_kernel(const float* __restrict__ A, const float* __restrict__ QK,
                          float* __restrict__ Out) {
    const int h = blockIdx.y;
    __shared__ float as[HD][HD];
    const int tid = threadIdx.x;
    for (int i = tid; i < HD * HD; i += 256) as[i / HD][i % HD] = A[(size_t)h * HD * HD + i];
    __syncthreads();
    const int hw = blockIdx.x * 256 + tid;
    const float* v = QK + (size_t)(2 * DIM + h * HD) * NPIX + hw;
    float acc[HD] = {};
    for (int d = 0; d < HD; ++d) {
        const float vv = v[(size_t)d * NPIX];
#pragma unroll
        for (int c = 0; c < HD; ++c) acc[c] += as[c][d] * vv;
    }
    float* o = Out + (size_t)(h * HD) * NPIX + hw;
#pragma unroll
    for (int c = 0; c < HD; ++c) o[(size_t)c * NPIX] = acc[c];
}

extern "C" void kernel_launch(void* const* d_in, const int* in_sizes, int n_in,
                              void* d_out, int out_size, void* d_ws, size_t ws_size,
                              hipStream_t stream) {
    const float* x      = (const float*)d_in[0];   // [4,384,96,96]
    const float* w_qkv  = (const float*)d_in[1];   // [1152,384]
    const float* w_dw   = (const float*)d_in[2];   // [1152,1,3,3]
    const float* w_proj = (const float*)d_in[3];   // [384,384]
    const float* temp   = (const float*)d_in[4];   // [8]
    float* out = (float*)d_out;

    char* ws = (char*)d_ws;
    const size_t SZ_QKV = (size_t)OC3 * NPIX * sizeof(float);   // 42.5 MB
    float* qkv_raw = (float*)(ws);                 // also reused for out_att
    float* qkv_dw  = (float*)(ws + SZ_QKV);
    float* out_att = qkv_raw;                      // qkv_raw dead after dwconv
    float* Fn      = (float*)(ws + 2 * SZ_QKV);                  // 768 floats (4KB slot!)
    float* Pp      = (float*)(ws + 2 * SZ_QKV + 4096);           // 8*NS*48*48 floats
    float* At      = (float*)(ws + 2 * SZ_QKV + 4096 +
                              (size_t)HEADS * NS * HD * HD * sizeof(float));  // 8*48*48

    for (int b = 0; b < 4; ++b) {
        const float* xb = x + (size_t)b * DIM * NPIX;
        float* ob = out + (size_t)b * DIM * NPIX;

        conv1x1_kernel<<<dim3(NPIX / 1024, OC3 / 32), 256, 0, stream>>>(w_qkv, xb, qkv_raw);
        dwconv_kernel<<<(size_t)OC3 * NPIX / 256, 256, 0, stream>>>(qkv_raw, w_dw, qkv_dw);
        norm_kernel<<<2 * DIM, 256, 0, stream>>>(qkv_dw, Fn);
        gram_kernel<<<dim3(NS, HEADS), 256, 0, stream>>>(qkv_dw, Pp);
        softmax_kernel<<<HEADS * HD, 64, 0, stream>>>(Pp, Fn, temp, At);
        av_kernel<<<dim3(NPIX / 256, HEADS), 256, 0, stream>>>(At, qkv_dw, out_att);
        conv1x1_kernel<<<dim3(NPIX / 1024, DIM / 32), 256, 0, stream>>>(w_proj, out_att, ob);
    }
}

// Round 3
// 830.548 us; speedup vs baseline: 7.7270x; 7.7270x over previous
//
#include <hip/hip_runtime.h>
#include <hip/hip_bf16.h>
#include <math.h>

#define DIM   384
#define HEADS 8
#define HD    48
#define HH    96
#define WW    96
#define NPIX  9216
#define OC3   1152
#define NS    8

typedef _Float16 f16x8 __attribute__((ext_vector_type(8)));
typedef float f32x4 __attribute__((ext_vector_type(4)));

// ---------------- transpose+cvt: in fp32 [384][NPIX] -> out f16 [NPIX][384]
__global__ void convert_xt_kernel(const float* __restrict__ In, _Float16* __restrict__ Out) {
    __shared__ _Float16 t[64][66];
    const int tid = threadIdx.x;
    const int n0 = blockIdx.x * 64, c0 = blockIdx.y * 64;
    const int col = tid & 63, rb = tid >> 6;
#pragma unroll
    for (int i = 0; i < 16; ++i) {
        const int r = i * 4 + rb;   // c-local
        t[r][col] = (_Float16)In[(size_t)(c0 + r) * NPIX + n0 + col];
    }
    __syncthreads();
#pragma unroll
    for (int i = 0; i < 16; ++i) {
        const int r = i * 4 + rb;   // n-local
        Out[(size_t)(n0 + r) * DIM + c0 + col] = t[col][r];
    }
}

// ---------------- W fp32 -> f16 elementwise (vec4)
__global__ void convert_w_kernel(const float* __restrict__ W, _Float16* __restrict__ O, int n4) {
    const int i = blockIdx.x * 256 + threadIdx.x;
    if (i >= n4) return;
    const float4 v = reinterpret_cast<const float4*>(W)[i];
    _Float16* o = O + (size_t)i * 4;
    o[0] = (_Float16)v.x; o[1] = (_Float16)v.y; o[2] = (_Float16)v.z; o[3] = (_Float16)v.w;
}

// ---------------- MFMA GEMM: Y[M][NPIX] = A16[M][384] * BT16[NPIX][384]^T
// 128x128 tile, BK=32, 4 waves (2x2), each wave 64x64 = 4x4 frags of 16x16.
__global__ void gemm16_kernel(const _Float16* __restrict__ A, const _Float16* __restrict__ BT,
                              float* __restrict__ Y) {
    __shared__ _Float16 As[128 * 32];
    __shared__ _Float16 Bs[128 * 32];
    const int tid = threadIdx.x;
    const int lane = tid & 63, wid = tid >> 6;
    const int m0 = blockIdx.y * 128, n0 = blockIdx.x * 128;
    const int wrow = (wid >> 1) * 64, wcol = (wid & 1) * 64;
    f32x4 acc[4][4] = {};
    for (int ks = 0; ks < 12; ++ks) {
        const int k0 = ks * 32;
        __syncthreads();
#pragma unroll
        for (int issue = 0; issue < 2; ++issue) {
            const int bytepos = issue * 4096 + wid * 1024 + lane * 16;
            const int row = bytepos >> 6, kp = (bytepos & 63) >> 1;
            const _Float16* ga = &A[(size_t)(m0 + row) * 384 + k0 + kp];
            const _Float16* gb = &BT[(size_t)(n0 + row) * 384 + k0 + kp];
            __builtin_amdgcn_global_load_lds(
                (const __attribute__((address_space(1))) void*)ga,
                (__attribute__((address_space(3))) void*)((char*)As + issue * 4096 + wid * 1024),
                16, 0, 0);
            __builtin_amdgcn_global_load_lds(
                (const __attribute__((address_space(1))) void*)gb,
                (__attribute__((address_space(3))) void*)((char*)Bs + issue * 4096 + wid * 1024),
                16, 0, 0);
        }
        __syncthreads();
        f16x8 af[4], bf[4];
#pragma unroll
        for (int mi = 0; mi < 4; ++mi)
            af[mi] = *(const f16x8*)&As[(wrow + mi * 16 + (lane & 15)) * 32 + (lane >> 4) * 8];
#pragma unroll
        for (int ni = 0; ni < 4; ++ni)
            bf[ni] = *(const f16x8*)&Bs[(wcol + ni * 16 + (lane & 15)) * 32 + (lane >> 4) * 8];
#pragma unroll
        for (int mi = 0; mi < 4; ++mi)
#pragma unroll
            for (int ni = 0; ni < 4; ++ni)
                acc[mi][ni] = __builtin_amdgcn_mfma_f32_16x16x32_f16(af[mi], bf[ni], acc[mi][ni], 0, 0, 0);
    }
    // C-write: col = lane&15, row = (lane>>4)*4 + r   [m89-verified layout]
#pragma unroll
    for (int mi = 0; mi < 4; ++mi)
#pragma unroll
        for (int ni = 0; ni < 4; ++ni) {
            const int gm = m0 + wrow + mi * 16 + (lane >> 4) * 4;
            const int gn = n0 + wcol + ni * 16 + (lane & 15);
#pragma unroll
            for (int r = 0; r < 4; ++r)
                Y[(size_t)(gm + r) * NPIX + gn] = acc[mi][ni][r];
        }
}

// ---------------- depthwise 3x3, pad=1
__global__ void dwconv_kernel(const float* __restrict__ In, const float* __restrict__ Wd,
                              float* __restrict__ Out) {
    const int idx = blockIdx.x * 256 + threadIdx.x;
    const int ch = idx / NPIX;
    const int p  = idx % NPIX;
    const int y = p / WW, x = p % WW;
    const float* wp = &Wd[ch * 9];
    const float* ip = &In[ch * NPIX];
    float acc = 0.f;
#pragma unroll
    for (int dy = -1; dy <= 1; ++dy) {
        const int yy = y + dy;
        if (yy < 0 || yy >= HH) continue;
#pragma unroll
        for (int dx = -1; dx <= 1; ++dx) {
            const int xx = x + dx;
            if (xx < 0 || xx >= WW) continue;
            acc += wp[(dy + 1) * 3 + (dx + 1)] * ip[yy * WW + xx];
        }
    }
    Out[idx] = acc;
}

// ---------------- 1/max(||row||,eps) for q rows [0,384) and k rows [384,768)
__global__ void norm_kernel(const float* __restrict__ QK, float* __restrict__ F) {
    const int row = blockIdx.x;
    const float* src = QK + (size_t)row * NPIX;
    const int tid = threadIdx.x;
    float s = 0.f;
    for (int i = tid; i < NPIX / 4; i += 256) {
        const float4 v = reinterpret_cast<const float4*>(src)[i];
        s += v.x * v.x + v.y * v.y + v.z * v.z + v.w * v.w;
    }
    for (int off = 32; off; off >>= 1) s += __shfl_down(s, off);
    __shared__ float red[4];
    if ((tid & 63) == 0) red[tid >> 6] = s;
    __syncthreads();
    if (tid == 0) {
        const float t = red[0] + red[1] + red[2] + red[3];
        F[row] = 1.f / fmaxf(sqrtf(t), 1e-12f);
    }
}

// ---------------- partial gram P[h,s,c,d] = sum_{n chunk s} q[c,n]*k[d,n]
__global__ void gram_kernel(const float* __restrict__ QK, float* __restrict__ P) {
    const int h = blockIdx.y, s = blockIdx.x;
    const int n0 = s * (NPIX / NS);
    const float* q = QK + (size_t)(h * HD) * NPIX;
    const float* k = QK + (size_t)(DIM + h * HD) * NPIX;
    __shared__ float qs[HD][132];
    __shared__ float ks[HD][132];
    const int tid = threadIdx.x;
    const int c0 = (tid >> 4) * 3, d0 = (tid & 15) * 3;
    float acc[3][3] = {};
    for (int nb = 0; nb < NPIX / NS; nb += 128) {
        __syncthreads();
        for (int i = tid; i < HD * 32; i += 256) {
            const int r = i / 32, cc = (i % 32) * 4;
            *reinterpret_cast<float4*>(&qs[r][cc]) =
                *reinterpret_cast<const float4*>(&q[(size_t)r * NPIX + n0 + nb + cc]);
            *reinterpret_cast<float4*>(&ks[r][cc]) =
                *reinterpret_cast<const float4*>(&k[(size_t)r * NPIX + n0 + nb + cc]);
        }
        __syncthreads();
        for (int n = 0; n < 128; ++n) {
            float qv[3], kv[3];
#pragma unroll
            for (int i = 0; i < 3; ++i) { qv[i] = qs[c0 + i][n]; kv[i] = ks[d0 + i][n]; }
#pragma unroll
            for (int i = 0; i < 3; ++i)
#pragma unroll
                for (int j = 0; j < 3; ++j) acc[i][j] += qv[i] * kv[j];
        }
    }
#pragma unroll
    for (int i = 0; i < 3; ++i)
#pragma unroll
        for (int j = 0; j < 3; ++j)
            P[((size_t)(h * NS + s) * HD + c0 + i) * HD + d0 + j] = acc[i][j];
}

// ---------------- reduce partials, scale by norms+temp, softmax over d
__global__ void softmax_kernel(const float* __restrict__ P, const float* __restrict__ F,
                               const float* __restrict__ temp, float* __restrict__ A) {
    const int h = blockIdx.x / HD, c = blockIdx.x % HD;
    const int d = threadIdx.x;
    float val = 0.f, v = -INFINITY;
    if (d < HD) {
        float sum = 0.f;
        for (int s = 0; s < NS; ++s) sum += P[((size_t)(h * NS + s) * HD + c) * HD + d];
        val = sum * F[h * HD + c] * F[DIM + h * HD + d] * temp[h];
        v = val;
    }
    float m = v;
    for (int off = 32; off; off >>= 1) m = fmaxf(m, __shfl_xor(m, off));
    const float e = (d < HD) ? expf(val - m) : 0.f;
    float se = e;
    for (int off = 32; off; off >>= 1) se += __shfl_xor(se, off);
    if (d < HD) A[(size_t)(h * HD + c) * HD + d] = e / se;
}

// ---------------- out[c,hw] = sum_d attn[c,d] * v[d,hw] per head
__global__ void av_kernel(const float* __restrict__ A, const float* __restrict__ QK,
                          float* __restrict__ Out) {
    const int h = blockIdx.y;
    __shared__ float as[HD][HD];
    const int tid = threadIdx.x;
    for (int i = tid; i < HD * HD; i += 256) as[i / HD][i % HD] = A[(size_t)h * HD * HD + i];
    __syncthreads();
    const int hw = blockIdx.x * 256 + tid;
    const float* v = QK + (size_t)(2 * DIM + h * HD) * NPIX + hw;
    float acc[HD] = {};
    for (int d = 0; d < HD; ++d) {
        const float vv = v[(size_t)d * NPIX];
#pragma unroll
        for (int c = 0; c < HD; ++c) acc[c] += as[c][d] * vv;
    }
    float* o = Out + (size_t)(h * HD) * NPIX + hw;
#pragma unroll
    for (int c = 0; c < HD; ++c) o[(size_t)c * NPIX] = acc[c];
}

extern "C" void kernel_launch(void* const* d_in, const int* in_sizes, int n_in,
                              void* d_out, int out_size, void* d_ws, size_t ws_size,
                              hipStream_t stream) {
    const float* x      = (const float*)d_in[0];
    const float* w_qkv  = (const float*)d_in[1];
    const float* w_dw   = (const float*)d_in[2];
    const float* w_proj = (const float*)d_in[3];
    const float* temp   = (const float*)d_in[4];
    float* out = (float*)d_out;

    char* ws = (char*)d_ws;
    const size_t SZ_QKV = (size_t)OC3 * NPIX * sizeof(float);     // 42.5 MB
    float*     qkv_raw = (float*)(ws);                            // also out_att
    float*     qkv_dw  = (float*)(ws + SZ_QKV);
    float*     out_att = qkv_raw;
    _Float16*  XT      = (_Float16*)qkv_dw;   // overlays qkv_dw: dead window before dwconv / after av
    _Float16*  W16q    = (_Float16*)(ws + 2 * SZ_QKV);            // 1152*384
    _Float16*  W16p    = (_Float16*)(ws + 2 * SZ_QKV + (size_t)OC3 * DIM * 2);
    char*      tail    = ws + 2 * SZ_QKV + (size_t)OC3 * DIM * 2 + (size_t)DIM * DIM * 2;
    float*     Fn      = (float*)tail;                            // 768 (4KB slot)
    float*     Pp      = (float*)(tail + 4096);                   // 8*NS*48*48
    float*     At      = (float*)(tail + 4096 + (size_t)HEADS * NS * HD * HD * 4);

    convert_w_kernel<<<(OC3 * DIM / 4 + 255) / 256, 256, 0, stream>>>(w_qkv, W16q, OC3 * DIM / 4);
    convert_w_kernel<<<(DIM * DIM / 4 + 255) / 256, 256, 0, stream>>>(w_proj, W16p, DIM * DIM / 4);

    for (int b = 0; b < 4; ++b) {
        const float* xb = x + (size_t)b * DIM * NPIX;
        float* ob = out + (size_t)b * DIM * NPIX;

        convert_xt_kernel<<<dim3(NPIX / 64, DIM / 64), 256, 0, stream>>>(xb, XT);
        gemm16_kernel<<<dim3(NPIX / 128, OC3 / 128), 256, 0, stream>>>(W16q, XT, qkv_raw);
        dwconv_kernel<<<(size_t)OC3 * NPIX / 256, 256, 0, stream>>>(qkv_raw, w_dw, qkv_dw);
        norm_kernel<<<2 * DIM, 256, 0, stream>>>(qkv_dw, Fn);
        gram_kernel<<<dim3(NS, HEADS), 256, 0, stream>>>(qkv_dw, Pp);
        softmax_kernel<<<HEADS * HD, 64, 0, stream>>>(Pp, Fn, temp, At);
        av_kernel<<<dim3(NPIX / 256, HEADS), 256, 0, stream>>>(At, qkv_dw, out_att);
        convert_xt_kernel<<<dim3(NPIX / 64, DIM / 64), 256, 0, stream>>>(out_att, XT);
        gemm16_kernel<<<dim3(NPIX / 128, DIM / 128), 256, 0, stream>>>(W16p, XT, ob);
    }
}

// Round 4
// 390.044 us; speedup vs baseline: 16.4537x; 2.1294x over previous
//
#include <hip/hip_runtime.h>
#include <hip/hip_bf16.h>
#include <math.h>

#define DIM   384
#define HEADS 8
#define HD    48
#define HH    96
#define WW    96
#define NPIX  9216
#define OC3   1152
#define NCH   36      // gram n-chunks (36*256 = 9216)

typedef _Float16 f16x8 __attribute__((ext_vector_type(8)));
typedef _Float16 f16x4 __attribute__((ext_vector_type(4)));
typedef _Float16 f16x2 __attribute__((ext_vector_type(2)));
typedef float f32x4 __attribute__((ext_vector_type(4)));

// ---------------- x fp32 [384][NPIX] -> XT f16 [NPIX][384]
__global__ void convert_xt_kernel(const float* __restrict__ In, _Float16* __restrict__ Out) {
    __shared__ _Float16 t[64][66];
    const int tid = threadIdx.x;
    const int n0 = blockIdx.x * 64, c0 = blockIdx.y * 64;
    const int col = tid & 63, rb = tid >> 6;
#pragma unroll
    for (int i = 0; i < 16; ++i) {
        const int r = i * 4 + rb;
        t[r][col] = (_Float16)In[(size_t)(c0 + r) * NPIX + n0 + col];
    }
    __syncthreads();
#pragma unroll
    for (int i = 0; i < 16; ++i) {
        const int r = i * 4 + rb;
        Out[(size_t)(n0 + r) * DIM + c0 + col] = t[col][r];
    }
}

// ---------------- W fp32 -> f16
__global__ void convert_w_kernel(const float* __restrict__ W, _Float16* __restrict__ O, int n4) {
    const int i = blockIdx.x * 256 + threadIdx.x;
    if (i >= n4) return;
    const float4 v = reinterpret_cast<const float4*>(W)[i];
    _Float16* o = O + (size_t)i * 4;
    o[0] = (_Float16)v.x; o[1] = (_Float16)v.y; o[2] = (_Float16)v.z; o[3] = (_Float16)v.w;
}

// ---------------- MFMA GEMM: Y[M][NPIX] = A16[M][384] * BT16[NPIX][384]^T
template<typename OutT>
__global__ void gemm16_kernel(const _Float16* __restrict__ A, const _Float16* __restrict__ BT,
                              OutT* __restrict__ Y) {
    __shared__ _Float16 As[128 * 32];
    __shared__ _Float16 Bs[128 * 32];
    const int tid = threadIdx.x;
    const int lane = tid & 63, wid = tid >> 6;
    const int m0 = blockIdx.y * 128, n0 = blockIdx.x * 128;
    const int wrow = (wid >> 1) * 64, wcol = (wid & 1) * 64;
    f32x4 acc[4][4] = {};
    for (int ks = 0; ks < 12; ++ks) {
        const int k0 = ks * 32;
        __syncthreads();
#pragma unroll
        for (int issue = 0; issue < 2; ++issue) {
            const int bytepos = issue * 4096 + wid * 1024 + lane * 16;
            const int row = bytepos >> 6, kp = (bytepos & 63) >> 1;
            const _Float16* ga = &A[(size_t)(m0 + row) * 384 + k0 + kp];
            const _Float16* gb = &BT[(size_t)(n0 + row) * 384 + k0 + kp];
            __builtin_amdgcn_global_load_lds(
                (const __attribute__((address_space(1))) void*)ga,
                (__attribute__((address_space(3))) void*)((char*)As + issue * 4096 + wid * 1024),
                16, 0, 0);
            __builtin_amdgcn_global_load_lds(
                (const __attribute__((address_space(1))) void*)gb,
                (__attribute__((address_space(3))) void*)((char*)Bs + issue * 4096 + wid * 1024),
                16, 0, 0);
        }
        __syncthreads();
        f16x8 af[4], bf[4];
#pragma unroll
        for (int mi = 0; mi < 4; ++mi)
            af[mi] = *(const f16x8*)&As[(wrow + mi * 16 + (lane & 15)) * 32 + (lane >> 4) * 8];
#pragma unroll
        for (int ni = 0; ni < 4; ++ni)
            bf[ni] = *(const f16x8*)&Bs[(wcol + ni * 16 + (lane & 15)) * 32 + (lane >> 4) * 8];
#pragma unroll
        for (int mi = 0; mi < 4; ++mi)
#pragma unroll
            for (int ni = 0; ni < 4; ++ni)
                acc[mi][ni] = __builtin_amdgcn_mfma_f32_16x16x32_f16(af[mi], bf[ni], acc[mi][ni], 0, 0, 0);
    }
#pragma unroll
    for (int mi = 0; mi < 4; ++mi)
#pragma unroll
        for (int ni = 0; ni < 4; ++ni) {
            const int gm = m0 + wrow + mi * 16 + (lane >> 4) * 4;
            const int gn = n0 + wcol + ni * 16 + (lane & 15);
#pragma unroll
            for (int r = 0; r < 4; ++r)
                Y[(size_t)(gm + r) * NPIX + gn] = (OutT)acc[mi][ni][r];
        }
}

// ---------------- depthwise 3x3 pad=1, f16 in/out, 4 px/thread
__global__ void dwconv16_kernel(const _Float16* __restrict__ In, const float* __restrict__ Wd,
                                _Float16* __restrict__ Out) {
    const int ch = blockIdx.y;
    const int p0 = blockIdx.x * 1024 + threadIdx.x * 4;   // multiple of 4; 96%4==0 -> same row
    const int y = p0 / WW, x0 = p0 % WW;
    const float* w = &Wd[ch * 9];
    const _Float16* ip = In + (size_t)ch * NPIX;
    float o0 = 0.f, o1 = 0.f, o2 = 0.f, o3 = 0.f;
#pragma unroll
    for (int dy = -1; dy <= 1; ++dy) {
        const int yy = y + dy;
        if (yy < 0 || yy >= HH) continue;
        const _Float16* row = ip + yy * WW;
        const f16x4 mid = *(const f16x4*)&row[x0];
        const float v1 = (float)mid[0], v2 = (float)mid[1], v3 = (float)mid[2], v4 = (float)mid[3];
        const float v0 = (x0 > 0) ? (float)row[x0 - 1] : 0.f;
        const float v5 = (x0 + 4 < WW) ? (float)row[x0 + 4] : 0.f;
        const float w0 = w[(dy + 1) * 3], w1 = w[(dy + 1) * 3 + 1], w2 = w[(dy + 1) * 3 + 2];
        o0 += w0 * v0 + w1 * v1 + w2 * v2;
        o1 += w0 * v1 + w1 * v2 + w2 * v3;
        o2 += w0 * v2 + w1 * v3 + w2 * v4;
        o3 += w0 * v3 + w1 * v4 + w2 * v5;
    }
    f16x4 r;
    r[0] = (_Float16)o0; r[1] = (_Float16)o1; r[2] = (_Float16)o2; r[3] = (_Float16)o3;
    *(f16x4*)&Out[(size_t)ch * NPIX + p0] = r;
}

// ---------------- 1/max(||row||,eps) for rows [0,768) of f16 qkv_dw
__global__ void norm16_kernel(const _Float16* __restrict__ QK, float* __restrict__ F) {
    const int row = blockIdx.x;
    const f16x8* src = (const f16x8*)(QK + (size_t)row * NPIX);
    const int tid = threadIdx.x;
    float s = 0.f;
    for (int i = tid; i < NPIX / 8; i += 256) {
        const f16x8 v = src[i];
#pragma unroll
        for (int j = 0; j < 8; ++j) { const float f = (float)v[j]; s += f * f; }
    }
    for (int off = 32; off; off >>= 1) s += __shfl_down(s, off);
    __shared__ float red[4];
    if ((tid & 63) == 0) red[tid >> 6] = s;
    __syncthreads();
    if (tid == 0) {
        const float t = red[0] + red[1] + red[2] + red[3];
        F[row] = 1.f / fmaxf(sqrtf(t), 1e-12f);
    }
}

// ---------------- MFMA gram: P[h][s][48][48] partial over n-chunk s (256 n each)
// grid (NCH, HEADS), block 128 = 2 waves; each wave does 4 K-steps of 32.
__global__ void gram16_kernel(const _Float16* __restrict__ QK, float* __restrict__ P) {
    const int h = blockIdx.y, s = blockIdx.x;
    const int tid = threadIdx.x;
    const int lane = tid & 63, wave = tid >> 6;
    const _Float16* q = QK + (size_t)(h * HD) * NPIX;
    const _Float16* k = QK + (size_t)(DIM + h * HD) * NPIX;
    const int rowa = lane & 15, koff = (lane >> 4) * 8;
    f32x4 acc[3][3] = {};
#pragma unroll
    for (int kk = 0; kk < 4; ++kk) {
        const int nk = s * 256 + wave * 128 + kk * 32 + koff;
        f16x8 aq[3], bk[3];
#pragma unroll
        for (int i = 0; i < 3; ++i)
            aq[i] = *(const f16x8*)&q[(size_t)(i * 16 + rowa) * NPIX + nk];
#pragma unroll
        for (int j = 0; j < 3; ++j)
            bk[j] = *(const f16x8*)&k[(size_t)(j * 16 + rowa) * NPIX + nk];
#pragma unroll
        for (int i = 0; i < 3; ++i)
#pragma unroll
            for (int j = 0; j < 3; ++j)
                acc[i][j] = __builtin_amdgcn_mfma_f32_16x16x32_f16(aq[i], bk[j], acc[i][j], 0, 0, 0);
    }
    __shared__ float red[2][HD][HD];
#pragma unroll
    for (int i = 0; i < 3; ++i)
#pragma unroll
        for (int j = 0; j < 3; ++j)
#pragma unroll
            for (int r = 0; r < 4; ++r)
                red[wave][i * 16 + (lane >> 4) * 4 + r][j * 16 + (lane & 15)] = acc[i][j][r];
    __syncthreads();
    float* pp = P + (size_t)(h * NCH + s) * HD * HD;
    for (int idx = tid; idx < HD * HD; idx += 128)
        pp[idx] = (&red[0][0][0])[idx] + (&red[1][0][0])[idx];
}

// ---------------- reduce partials, scale by norms+temp, softmax over d
__global__ void softmax_kernel(const float* __restrict__ P, const float* __restrict__ F,
                               const float* __restrict__ temp, float* __restrict__ A) {
    const int h = blockIdx.x / HD, c = blockIdx.x % HD;
    const int d = threadIdx.x;
    float val = 0.f, v = -INFINITY;
    if (d < HD) {
        float sum = 0.f;
        for (int s = 0; s < NCH; ++s) sum += P[((size_t)(h * NCH + s) * HD + c) * HD + d];
        val = sum * F[h * HD + c] * F[DIM + h * HD + d] * temp[h];
        v = val;
    }
    float m = v;
    for (int off = 32; off; off >>= 1) m = fmaxf(m, __shfl_xor(m, off));
    const float e = (d < HD) ? expf(val - m) : 0.f;
    float se = e;
    for (int off = 32; off; off >>= 1) se += __shfl_xor(se, off);
    if (d < HD) A[(size_t)(h * HD + c) * HD + d] = e / se;
}

// ---------------- av + transposed f16 write: attT[n][384]
// grid (NPIX/512, HEADS), block 256; 2 px/thread.
__global__ void av16_kernel(const float* __restrict__ At, const _Float16* __restrict__ QKdw,
                            unsigned* __restrict__ OutT) {
    const int h = blockIdx.y;
    __shared__ float as[HD][HD];
    __shared__ unsigned tu[512][25];
    const int tid = threadIdx.x;
    for (int i = tid; i < HD * HD; i += 256) as[i / HD][i % HD] = At[(size_t)h * HD * HD + i];
    __syncthreads();
    const int n0 = blockIdx.x * 512;
    const int n = n0 + tid * 2;
    const _Float16* v = QKdw + (size_t)(2 * DIM + h * HD) * NPIX + n;
    float acca[HD] = {}, accb[HD] = {};
    for (int d = 0; d < HD; ++d) {
        const f16x2 vv = *(const f16x2*)&v[(size_t)d * NPIX];
        const float va = (float)vv[0], vb = (float)vv[1];
#pragma unroll
        for (int c = 0; c < HD; ++c) {
            const float a = as[c][d];
            acca[c] += a * va; accb[c] += a * vb;
        }
    }
#pragma unroll
    for (int cc = 0; cc < 24; ++cc) {
        union { _Float16 hh[2]; unsigned u; } pa, pb;
        pa.hh[0] = (_Float16)acca[2 * cc]; pa.hh[1] = (_Float16)acca[2 * cc + 1];
        pb.hh[0] = (_Float16)accb[2 * cc]; pb.hh[1] = (_Float16)accb[2 * cc + 1];
        tu[tid * 2][cc] = pa.u;
        tu[tid * 2 + 1][cc] = pb.u;
    }
    __syncthreads();
#pragma unroll
    for (int i = 0; i < 48; ++i) {
        const int idx = i * 256 + tid;       // < 12288
        const int r = idx / 24, c = idx % 24;
        OutT[(size_t)(n0 + r) * 192 + h * 24 + c] = tu[r][c];
    }
}

extern "C" void kernel_launch(void* const* d_in, const int* in_sizes, int n_in,
                              void* d_out, int out_size, void* d_ws, size_t ws_size,
                              hipStream_t stream) {
    const float* x      = (const float*)d_in[0];
    const float* w_qkv  = (const float*)d_in[1];
    const float* w_dw   = (const float*)d_in[2];
    const float* w_proj = (const float*)d_in[3];
    const float* temp   = (const float*)d_in[4];
    float* out = (float*)d_out;

    char* ws = (char*)d_ws;
    const size_t MB = 1024 * 1024;
    _Float16* XT      = (_Float16*)(ws);             // [NPIX][384] f16, 7.1 MB
    _Float16* qkv16   = (_Float16*)(ws + 8 * MB);    // [1152][NPIX] f16, 21.3 MB
    _Float16* qkvdw16 = (_Float16*)(ws + 30 * MB);   // [1152][NPIX] f16, 21.3 MB
    _Float16* attT16  = (_Float16*)(ws + 52 * MB);   // [NPIX][384] f16, 7.1 MB
    _Float16* W16q    = (_Float16*)(ws + 60 * MB);   // 1152*384
    _Float16* W16p    = (_Float16*)(ws + 61 * MB);   // 384*384
    float*    Fn      = (float*)(ws + 62 * MB);      // 768
    float*    Pp      = (float*)(ws + 62 * MB + 4096);                 // 8*36*2304 f32
    float*    At      = (float*)(ws + 62 * MB + 4096 + 2700 * 1024);   // 8*2304 f32

    convert_w_kernel<<<(OC3 * DIM / 4 + 255) / 256, 256, 0, stream>>>(w_qkv, W16q, OC3 * DIM / 4);
    convert_w_kernel<<<(DIM * DIM / 4 + 255) / 256, 256, 0, stream>>>(w_proj, W16p, DIM * DIM / 4);

    for (int b = 0; b < 4; ++b) {
        const float* xb = x + (size_t)b * DIM * NPIX;
        float* ob = out + (size_t)b * DIM * NPIX;

        convert_xt_kernel<<<dim3(NPIX / 64, DIM / 64), 256, 0, stream>>>(xb, XT);
        gemm16_kernel<_Float16><<<dim3(NPIX / 128, OC3 / 128), 256, 0, stream>>>(W16q, XT, qkv16);
        dwconv16_kernel<<<dim3(9, OC3), 256, 0, stream>>>(qkv16, w_dw, qkvdw16);
        norm16_kernel<<<2 * DIM, 256, 0, stream>>>(qkvdw16, Fn);
        gram16_kernel<<<dim3(NCH, HEADS), 128, 0, stream>>>(qkvdw16, Pp);
        softmax_kernel<<<HEADS * HD, 64, 0, stream>>>(Pp, Fn, temp, At);
        av16_kernel<<<dim3(NPIX / 512, HEADS), 256, 0, stream>>>(At, qkvdw16, (unsigned*)attT16);
        gemm16_kernel<float><<<dim3(NPIX / 128, DIM / 128), 256, 0, stream>>>(W16p, attT16, ob);
    }
}

// Round 5
// 248.901 us; speedup vs baseline: 25.7840x; 1.5671x over previous
//
#include <hip/hip_runtime.h>
#include <hip/hip_bf16.h>
#include <math.h>

#define DIM   384
#define HEADS 8
#define HD    48
#define HH    96
#define WW    96
#define NPIX  9216
#define OC3   1152
#define NCH   36      // gram n-chunks (36*256 = 9216)
#define NB    4

typedef _Float16 f16x8 __attribute__((ext_vector_type(8)));
typedef _Float16 f16x4 __attribute__((ext_vector_type(4)));
typedef _Float16 f16x2 __attribute__((ext_vector_type(2)));
typedef float f32x4 __attribute__((ext_vector_type(4)));

// ---------------- x fp32 [b][384][NPIX] -> XT f16 [b][NPIX][384]
__global__ void convert_xt_kernel(const float* __restrict__ In, _Float16* __restrict__ Out) {
    const int b = blockIdx.z;
    In  += (size_t)b * DIM * NPIX;
    Out += (size_t)b * NPIX * DIM;
    __shared__ _Float16 t[64][66];
    const int tid = threadIdx.x;
    const int n0 = blockIdx.x * 64, c0 = blockIdx.y * 64;
    const int col = tid & 63, rb = tid >> 6;
#pragma unroll
    for (int i = 0; i < 16; ++i) {
        const int r = i * 4 + rb;
        t[r][col] = (_Float16)In[(size_t)(c0 + r) * NPIX + n0 + col];
    }
    __syncthreads();
#pragma unroll
    for (int i = 0; i < 16; ++i) {
        const int r = i * 4 + rb;
        Out[(size_t)(n0 + r) * DIM + c0 + col] = t[col][r];
    }
}

// ---------------- W fp32 -> f16
__global__ void convert_w_kernel(const float* __restrict__ W, _Float16* __restrict__ O, int n4) {
    const int i = blockIdx.x * 256 + threadIdx.x;
    if (i >= n4) return;
    const float4 v = reinterpret_cast<const float4*>(W)[i];
    _Float16* o = O + (size_t)i * 4;
    o[0] = (_Float16)v.x; o[1] = (_Float16)v.y; o[2] = (_Float16)v.z; o[3] = (_Float16)v.w;
}

// ---------------- MFMA GEMM: Y[M][NPIX] = A16[M][384] * BT16[NPIX][384]^T
// 128x128 tile, BK=64, double-buffered LDS with prefetch-before-compute.
template<typename OutT>
__global__ void gemm16_kernel(const _Float16* __restrict__ A, const _Float16* __restrict__ BT,
                              OutT* __restrict__ Y, size_t bstride, size_t ystride) {
    __shared__ _Float16 As[2][128 * 64];   // 16KB each
    __shared__ _Float16 Bs[2][128 * 64];
    const int tid = threadIdx.x;
    const int lane = tid & 63, wid = tid >> 6;
    const int m0 = blockIdx.y * 128, n0 = blockIdx.x * 128;
    BT += (size_t)blockIdx.z * bstride;
    Y  += (size_t)blockIdx.z * ystride;
    const int wrow = (wid >> 1) * 64, wcol = (wid & 1) * 64;

    auto stage = [&](int buf, int t) {
        const int k0 = t * 64;
#pragma unroll
        for (int issue = 0; issue < 4; ++issue) {
            const int bytepos = issue * 4096 + wid * 1024 + lane * 16;
            const int row = bytepos >> 7, kp = (bytepos & 127) >> 1;
            __builtin_amdgcn_global_load_lds(
                (const __attribute__((address_space(1))) void*)&A[(size_t)(m0 + row) * 384 + k0 + kp],
                (__attribute__((address_space(3))) void*)((char*)&As[buf][0] + issue * 4096 + wid * 1024),
                16, 0, 0);
            __builtin_amdgcn_global_load_lds(
                (const __attribute__((address_space(1))) void*)&BT[(size_t)(n0 + row) * 384 + k0 + kp],
                (__attribute__((address_space(3))) void*)((char*)&Bs[buf][0] + issue * 4096 + wid * 1024),
                16, 0, 0);
        }
    };

    f32x4 acc[4][4] = {};
    stage(0, 0);
    __syncthreads();
    int cur = 0;
    for (int t = 0; t < 6; ++t) {
        if (t + 1 < 6) stage(cur ^ 1, t + 1);   // prefetch overlaps compute below
#pragma unroll
        for (int ksub = 0; ksub < 2; ++ksub) {
            f16x8 af[4], bf[4];
#pragma unroll
            for (int mi = 0; mi < 4; ++mi)
                af[mi] = *(const f16x8*)&As[cur][(wrow + mi * 16 + (lane & 15)) * 64 + ksub * 32 + (lane >> 4) * 8];
#pragma unroll
            for (int ni = 0; ni < 4; ++ni)
                bf[ni] = *(const f16x8*)&Bs[cur][(wcol + ni * 16 + (lane & 15)) * 64 + ksub * 32 + (lane >> 4) * 8];
#pragma unroll
            for (int mi = 0; mi < 4; ++mi)
#pragma unroll
                for (int ni = 0; ni < 4; ++ni)
                    acc[mi][ni] = __builtin_amdgcn_mfma_f32_16x16x32_f16(af[mi], bf[ni], acc[mi][ni], 0, 0, 0);
        }
        __syncthreads();   // drains prefetch vmcnt + protects cur swap
        cur ^= 1;
    }
#pragma unroll
    for (int mi = 0; mi < 4; ++mi)
#pragma unroll
        for (int ni = 0; ni < 4; ++ni) {
            const int gm = m0 + wrow + mi * 16 + (lane >> 4) * 4;
            const int gn = n0 + wcol + ni * 16 + (lane & 15);
#pragma unroll
            for (int r = 0; r < 4; ++r)
                Y[(size_t)(gm + r) * NPIX + gn] = (OutT)acc[mi][ni][r];
        }
}

// ---------------- depthwise 3x3 pad=1, f16 in/out, 4 px/thread
__global__ void dwconv16_kernel(const _Float16* __restrict__ In, const float* __restrict__ Wd,
                                _Float16* __restrict__ Out) {
    const int b = blockIdx.z, ch = blockIdx.y;
    In  += (size_t)b * OC3 * NPIX;
    Out += (size_t)b * OC3 * NPIX;
    const int p0 = blockIdx.x * 1024 + threadIdx.x * 4;
    const int y = p0 / WW, x0 = p0 % WW;
    const float* w = &Wd[ch * 9];
    const _Float16* ip = In + (size_t)ch * NPIX;
    float o0 = 0.f, o1 = 0.f, o2 = 0.f, o3 = 0.f;
#pragma unroll
    for (int dy = -1; dy <= 1; ++dy) {
        const int yy = y + dy;
        if (yy < 0 || yy >= HH) continue;
        const _Float16* row = ip + yy * WW;
        const f16x4 mid = *(const f16x4*)&row[x0];
        const float v1 = (float)mid[0], v2 = (float)mid[1], v3 = (float)mid[2], v4 = (float)mid[3];
        const float v0 = (x0 > 0) ? (float)row[x0 - 1] : 0.f;
        const float v5 = (x0 + 4 < WW) ? (float)row[x0 + 4] : 0.f;
        const float w0 = w[(dy + 1) * 3], w1 = w[(dy + 1) * 3 + 1], w2 = w[(dy + 1) * 3 + 2];
        o0 += w0 * v0 + w1 * v1 + w2 * v2;
        o1 += w0 * v1 + w1 * v2 + w2 * v3;
        o2 += w0 * v2 + w1 * v3 + w2 * v4;
        o3 += w0 * v3 + w1 * v4 + w2 * v5;
    }
    f16x4 r;
    r[0] = (_Float16)o0; r[1] = (_Float16)o1; r[2] = (_Float16)o2; r[3] = (_Float16)o3;
    *(f16x4*)&Out[(size_t)ch * NPIX + p0] = r;
}

// ---------------- MFMA gram + fused sumsq partials
// grid (NCH, HEADS, NB), block 128 = 2 waves
__global__ void gram16_kernel(const _Float16* __restrict__ QK, float* __restrict__ P,
                              float* __restrict__ SS) {
    const int h = blockIdx.y, s = blockIdx.x, b = blockIdx.z;
    QK += (size_t)b * OC3 * NPIX;
    const int tid = threadIdx.x;
    const int lane = tid & 63, wave = tid >> 6;
    const _Float16* q = QK + (size_t)(h * HD) * NPIX;
    const _Float16* k = QK + (size_t)(DIM + h * HD) * NPIX;
    const int rowa = lane & 15, koff = (lane >> 4) * 8;
    f32x4 acc[3][3] = {};
    float ssq[3] = {}, ssk[3] = {};
#pragma unroll
    for (int kk = 0; kk < 4; ++kk) {
        const int nk = s * 256 + wave * 128 + kk * 32 + koff;
        f16x8 aq[3], bk[3];
#pragma unroll
        for (int i = 0; i < 3; ++i)
            aq[i] = *(const f16x8*)&q[(size_t)(i * 16 + rowa) * NPIX + nk];
#pragma unroll
        for (int j = 0; j < 3; ++j)
            bk[j] = *(const f16x8*)&k[(size_t)(j * 16 + rowa) * NPIX + nk];
#pragma unroll
        for (int i = 0; i < 3; ++i)
#pragma unroll
            for (int j = 0; j < 8; ++j) {
                const float fq = (float)aq[i][j], fk = (float)bk[i][j];
                ssq[i] += fq * fq; ssk[i] += fk * fk;
            }
#pragma unroll
        for (int i = 0; i < 3; ++i)
#pragma unroll
            for (int j = 0; j < 3; ++j)
                acc[i][j] = __builtin_amdgcn_mfma_f32_16x16x32_f16(aq[i], bk[j], acc[i][j], 0, 0, 0);
    }
    // reduce sumsq across the 4 koff lane-groups (xor bits 4,5)
#pragma unroll
    for (int i = 0; i < 3; ++i) {
        ssq[i] += __shfl_xor(ssq[i], 16); ssq[i] += __shfl_xor(ssq[i], 32);
        ssk[i] += __shfl_xor(ssk[i], 16); ssk[i] += __shfl_xor(ssk[i], 32);
    }
    if (lane < 16) {
        float* ssb = SS + (((size_t)(b * HEADS + h) * NCH + s) * 2 + wave) * 96;
#pragma unroll
        for (int i = 0; i < 3; ++i) {
            ssb[i * 16 + lane]      = ssq[i];
            ssb[48 + i * 16 + lane] = ssk[i];
        }
    }
    __shared__ float red[2][HD][HD];
#pragma unroll
    for (int i = 0; i < 3; ++i)
#pragma unroll
        for (int j = 0; j < 3; ++j)
#pragma unroll
            for (int r = 0; r < 4; ++r)
                red[wave][i * 16 + (lane >> 4) * 4 + r][j * 16 + (lane & 15)] = acc[i][j][r];
    __syncthreads();
    float* pp = P + ((size_t)(b * HEADS + h) * NCH + s) * HD * HD;
    for (int idx = tid; idx < HD * HD; idx += 128)
        pp[idx] = (&red[0][0][0])[idx] + (&red[1][0][0])[idx];
}

// ---------------- reduce sumsq partials -> 1/max(||row||,eps);  rows: [b][768]
__global__ void normreduce_kernel(const float* __restrict__ SS, float* __restrict__ Fn) {
    const int idx = blockIdx.x * 256 + threadIdx.x;
    if (idx >= NB * 768) return;
    const int b = idx / 768, r = idx % 768;
    const int qk = r >= 384;
    const int h = (r - qk * 384) / HD, c = r % HD;
    const float* base = SS + ((size_t)(b * HEADS + h) * NCH) * 2 * 96 + qk * 48 + c;
    float s = 0.f;
    for (int u = 0; u < NCH * 2; ++u) s += base[u * 96];
    Fn[b * 768 + r] = 1.f / fmaxf(sqrtf(s), 1e-12f);
}

// ---------------- reduce gram partials, scale by norms+temp, softmax over d
__global__ void softmax_kernel(const float* __restrict__ P, const float* __restrict__ Fn,
                               const float* __restrict__ temp, float* __restrict__ A) {
    const int b = blockIdx.y;
    const int h = blockIdx.x / HD, c = blockIdx.x % HD;
    const float* F = Fn + b * 768;
    const float* Pb = P + (size_t)b * HEADS * NCH * HD * HD;
    const int d = threadIdx.x;
    float val = 0.f, v = -INFINITY;
    if (d < HD) {
        float sum = 0.f;
        for (int s = 0; s < NCH; ++s) sum += Pb[((size_t)(h * NCH + s) * HD + c) * HD + d];
        val = sum * F[h * HD + c] * F[DIM + h * HD + d] * temp[h];
        v = val;
    }
    float m = v;
    for (int off = 32; off; off >>= 1) m = fmaxf(m, __shfl_xor(m, off));
    const float e = (d < HD) ? expf(val - m) : 0.f;
    float se = e;
    for (int off = 32; off; off >>= 1) se += __shfl_xor(se, off);
    if (d < HD) A[((size_t)b * HEADS + h) * HD * HD + (size_t)c * HD + d] = e / se;
}

// ---------------- av + transposed f16 write: attT[b][n][384]
__global__ void av16_kernel(const float* __restrict__ At, const _Float16* __restrict__ QKdw,
                            unsigned* __restrict__ OutT) {
    const int b = blockIdx.z, h = blockIdx.y;
    At   += (size_t)b * HEADS * HD * HD;
    QKdw += (size_t)b * OC3 * NPIX;
    OutT += (size_t)b * NPIX * 192;
    __shared__ float as[HD][HD];
    __shared__ unsigned tu[512][25];
    const int tid = threadIdx.x;
    for (int i = tid; i < HD * HD; i += 256) as[i / HD][i % HD] = At[(size_t)h * HD * HD + i];
    __syncthreads();
    const int n0 = blockIdx.x * 512;
    const int n = n0 + tid * 2;
    const _Float16* v = QKdw + (size_t)(2 * DIM + h * HD) * NPIX + n;
    float acca[HD] = {}, accb[HD] = {};
    for (int d = 0; d < HD; ++d) {
        const f16x2 vv = *(const f16x2*)&v[(size_t)d * NPIX];
        const float va = (float)vv[0], vb = (float)vv[1];
#pragma unroll
        for (int c = 0; c < HD; ++c) {
            const float a = as[c][d];
            acca[c] += a * va; accb[c] += a * vb;
        }
    }
#pragma unroll
    for (int cc = 0; cc < 24; ++cc) {
        union { _Float16 hh[2]; unsigned u; } pa, pb;
        pa.hh[0] = (_Float16)acca[2 * cc]; pa.hh[1] = (_Float16)acca[2 * cc + 1];
        pb.hh[0] = (_Float16)accb[2 * cc]; pb.hh[1] = (_Float16)accb[2 * cc + 1];
        tu[tid * 2][cc] = pa.u;
        tu[tid * 2 + 1][cc] = pb.u;
    }
    __syncthreads();
#pragma unroll
    for (int i = 0; i < 48; ++i) {
        const int idx = i * 256 + tid;
        const int r = idx / 24, c = idx % 24;
        OutT[(size_t)(n0 + r) * 192 + h * 24 + c] = tu[r][c];
    }
}

extern "C" void kernel_launch(void* const* d_in, const int* in_sizes, int n_in,
                              void* d_out, int out_size, void* d_ws, size_t ws_size,
                              hipStream_t stream) {
    const float* x      = (const float*)d_in[0];
    const float* w_qkv  = (const float*)d_in[1];
    const float* w_dw   = (const float*)d_in[2];
    const float* w_proj = (const float*)d_in[3];
    const float* temp   = (const float*)d_in[4];
    float* out = (float*)d_out;

    char* ws = (char*)d_ws;
    const size_t SZ_XT   = (size_t)NB * NPIX * DIM * 2;      // 28.3 MB
    const size_t SZ_QKV  = (size_t)NB * OC3 * NPIX * 2;      // 84.9 MB
    _Float16* XT      = (_Float16*)(ws);
    _Float16* qkv16   = (_Float16*)(ws + SZ_XT);
    _Float16* qkvdw16 = (_Float16*)(ws + SZ_XT + SZ_QKV);
    _Float16* attT16  = qkv16;                                // overlays dead qkv16
    char* tail = ws + SZ_XT + 2 * SZ_QKV;
    _Float16* W16q = (_Float16*)(tail);                       // 884736 B
    _Float16* W16p = (_Float16*)(tail + 1024 * 1024);         // 294912 B
    float*    Fn   = (float*)(tail + 2 * 1024 * 1024);        // 4*768*4 = 12KB
    float*    Pp   = (float*)(tail + 2 * 1024 * 1024 + 65536);             // 10.6 MB
    float*    At   = (float*)(tail + 13 * 1024 * 1024);                    // 294912 B
    float*    SS   = (float*)(tail + 14 * 1024 * 1024);                    // 884736 B

    convert_w_kernel<<<(OC3 * DIM / 4 + 255) / 256, 256, 0, stream>>>(w_qkv, W16q, OC3 * DIM / 4);
    convert_w_kernel<<<(DIM * DIM / 4 + 255) / 256, 256, 0, stream>>>(w_proj, W16p, DIM * DIM / 4);

    convert_xt_kernel<<<dim3(NPIX / 64, DIM / 64, NB), 256, 0, stream>>>(x, XT);
    gemm16_kernel<_Float16><<<dim3(NPIX / 128, OC3 / 128, NB), 256, 0, stream>>>(
        W16q, XT, qkv16, (size_t)NPIX * DIM, (size_t)OC3 * NPIX);
    dwconv16_kernel<<<dim3(9, OC3, NB), 256, 0, stream>>>(qkv16, w_dw, qkvdw16);
    gram16_kernel<<<dim3(NCH, HEADS, NB), 128, 0, stream>>>(qkvdw16, Pp, SS);
    normreduce_kernel<<<(NB * 768 + 255) / 256, 256, 0, stream>>>(SS, Fn);
    softmax_kernel<<<dim3(HEADS * HD, NB), 64, 0, stream>>>(Pp, Fn, temp, At);
    av16_kernel<<<dim3(NPIX / 512, HEADS, NB), 256, 0, stream>>>(At, qkvdw16, (unsigned*)attT16);
    gemm16_kernel<float><<<dim3(NPIX / 128, DIM / 128, NB), 256, 0, stream>>>(
        W16p, attT16, out, (size_t)NPIX * DIM, (size_t)DIM * NPIX);
}

// Round 6
// 229.976 us; speedup vs baseline: 27.9058x; 1.0823x over previous
//
#include <hip/hip_runtime.h>
#include <hip/hip_bf16.h>
#include <math.h>

#define DIM   384
#define HEADS 8
#define HD    48
#define HH    96
#define WW    96
#define NPIX  9216
#define OC3   1152
#define NCH   36      // gram n-chunks (36*256 = 9216)
#define NB    4

typedef _Float16 f16x8 __attribute__((ext_vector_type(8)));
typedef _Float16 f16x4 __attribute__((ext_vector_type(4)));
typedef _Float16 f16x2 __attribute__((ext_vector_type(2)));
typedef float f32x4 __attribute__((ext_vector_type(4)));

// ---------------- x fp32 [b][384][NPIX] -> XT f16 [b][NPIX][384]
// 128c x 64n tiles: 256B read rows AND 256B write rows.
__global__ void convert_xt_kernel(const float* __restrict__ In, _Float16* __restrict__ Out) {
    const int b = blockIdx.z;
    In  += (size_t)b * DIM * NPIX;
    Out += (size_t)b * NPIX * DIM;
    __shared__ _Float16 t[128][66];
    const int tid = threadIdx.x;
    const int n0 = blockIdx.x * 64, c0 = blockIdx.y * 128;
    const int col = tid & 63, rb = tid >> 6;
#pragma unroll
    for (int i = 0; i < 32; ++i) {
        const int r = i * 4 + rb;   // c-local
        t[r][col] = (_Float16)In[(size_t)(c0 + r) * NPIX + n0 + col];
    }
    __syncthreads();
#pragma unroll
    for (int i = 0; i < 16; ++i) {
        const int n = i * 4 + rb;   // n-local
        f16x2 v;
        v[0] = t[col * 2][n];
        v[1] = t[col * 2 + 1][n];
        *(f16x2*)&Out[(size_t)(n0 + n) * DIM + c0 + col * 2] = v;
    }
}

// ---------------- W fp32 -> f16
__global__ void convert_w_kernel(const float* __restrict__ W, _Float16* __restrict__ O, int n4) {
    const int i = blockIdx.x * 256 + threadIdx.x;
    if (i >= n4) return;
    const float4 v = reinterpret_cast<const float4*>(W)[i];
    _Float16* o = O + (size_t)i * 4;
    o[0] = (_Float16)v.x; o[1] = (_Float16)v.y; o[2] = (_Float16)v.z; o[3] = (_Float16)v.w;
}

// ---------------- MFMA GEMM: Y[M][NPIX] = A16[M][384] * BT16[NPIX][384]^T
// 128x128 tile, BK=64, double-buffered LDS, prefetch-before-compute.
// LDS bank-conflict fix: XOR swizzle (byte ^= (row&7)<<4), applied as
// pre-swizzled GLOBAL source (linear global_load_lds dest) + swizzled ds_read.
template<typename OutT>
__global__ void gemm16_kernel(const _Float16* __restrict__ A, const _Float16* __restrict__ BT,
                              OutT* __restrict__ Y, size_t bstride, size_t ystride) {
    __shared__ _Float16 As[2][128 * 64];   // 16KB each
    __shared__ _Float16 Bs[2][128 * 64];
    const int tid = threadIdx.x;
    const int lane = tid & 63, wid = tid >> 6;
    const int m0 = blockIdx.y * 128, n0 = blockIdx.x * 128;
    BT += (size_t)blockIdx.z * bstride;
    Y  += (size_t)blockIdx.z * ystride;
    const int wrow = (wid >> 1) * 64, wcol = (wid & 1) * 64;

    auto stage = [&](int buf, int t) {
        const int k0 = t * 64;
#pragma unroll
        for (int issue = 0; issue < 4; ++issue) {
            const int p = issue * 4096 + wid * 1024 + lane * 16;   // linear LDS byte pos
            const int row = p >> 7;
            const int cb  = (p & 127) ^ ((row & 7) << 4);          // swizzled source col-bytes
            const int kp  = cb >> 1;
            __builtin_amdgcn_global_load_lds(
                (const __attribute__((address_space(1))) void*)&A[(size_t)(m0 + row) * 384 + k0 + kp],
                (__attribute__((address_space(3))) void*)((char*)&As[buf][0] + issue * 4096 + wid * 1024),
                16, 0, 0);
            __builtin_amdgcn_global_load_lds(
                (const __attribute__((address_space(1))) void*)&BT[(size_t)(n0 + row) * 384 + k0 + kp],
                (__attribute__((address_space(3))) void*)((char*)&Bs[buf][0] + issue * 4096 + wid * 1024),
                16, 0, 0);
        }
    };

    f32x4 acc[4][4] = {};
    stage(0, 0);
    __syncthreads();
    int cur = 0;
    for (int t = 0; t < 6; ++t) {
        if (t + 1 < 6) stage(cur ^ 1, t + 1);   // prefetch overlaps compute below
        const char* Ab = (const char*)&As[cur][0];
        const char* Bb = (const char*)&Bs[cur][0];
#pragma unroll
        for (int ksub = 0; ksub < 2; ++ksub) {
            const int cb = ksub * 64 + (lane >> 4) * 16;   // byte col within row
            f16x8 af[4], bf[4];
#pragma unroll
            for (int mi = 0; mi < 4; ++mi) {
                const int r = wrow + mi * 16 + (lane & 15);
                af[mi] = *(const f16x8*)(Ab + r * 128 + (cb ^ ((r & 7) << 4)));
            }
#pragma unroll
            for (int ni = 0; ni < 4; ++ni) {
                const int r = wcol + ni * 16 + (lane & 15);
                bf[ni] = *(const f16x8*)(Bb + r * 128 + (cb ^ ((r & 7) << 4)));
            }
#pragma unroll
            for (int mi = 0; mi < 4; ++mi)
#pragma unroll
                for (int ni = 0; ni < 4; ++ni)
                    acc[mi][ni] = __builtin_amdgcn_mfma_f32_16x16x32_f16(af[mi], bf[ni], acc[mi][ni], 0, 0, 0);
        }
        __syncthreads();   // drains prefetch vmcnt + protects cur swap
        cur ^= 1;
    }
#pragma unroll
    for (int mi = 0; mi < 4; ++mi)
#pragma unroll
        for (int ni = 0; ni < 4; ++ni) {
            const int gm = m0 + wrow + mi * 16 + (lane >> 4) * 4;
            const int gn = n0 + wcol + ni * 16 + (lane & 15);
#pragma unroll
            for (int r = 0; r < 4; ++r)
                Y[(size_t)(gm + r) * NPIX + gn] = (OutT)acc[mi][ni][r];
        }
}

// ---------------- depthwise 3x3 pad=1, f16 in/out, 8 px/thread
__global__ void dwconv16_kernel(const _Float16* __restrict__ In, const float* __restrict__ Wd,
                                _Float16* __restrict__ Out) {
    const int idx = blockIdx.x * 256 + threadIdx.x;   // over NB*OC3*1152
    const int ci = idx / 1152;                         // channel-image [0, NB*OC3)
    const int p0 = (idx - ci * 1152) * 8;              // 96%8==0 -> same image row
    const int ch = ci % OC3;
    const _Float16* ip = In + (size_t)ci * NPIX;
    const float* w = &Wd[ch * 9];
    const int y = p0 / WW, x0 = p0 % WW;
    float o[8] = {};
#pragma unroll
    for (int dy = -1; dy <= 1; ++dy) {
        const int yy = y + dy;
        if (yy < 0 || yy >= HH) continue;
        const _Float16* row = ip + yy * WW;
        const f16x8 mid = *(const f16x8*)&row[x0];
        float v[10];
        v[0] = (x0 > 0) ? (float)row[x0 - 1] : 0.f;
        v[9] = (x0 + 8 < WW) ? (float)row[x0 + 8] : 0.f;
#pragma unroll
        for (int j = 0; j < 8; ++j) v[j + 1] = (float)mid[j];
        const float w0 = w[(dy + 1) * 3], w1 = w[(dy + 1) * 3 + 1], w2 = w[(dy + 1) * 3 + 2];
#pragma unroll
        for (int j = 0; j < 8; ++j) o[j] += w0 * v[j] + w1 * v[j + 1] + w2 * v[j + 2];
    }
    f16x8 r;
#pragma unroll
    for (int j = 0; j < 8; ++j) r[j] = (_Float16)o[j];
    *(f16x8*)&Out[(size_t)ci * NPIX + p0] = r;
}

// ---------------- MFMA gram + fused sumsq partials
// grid (NCH, HEADS, NB), block 128 = 2 waves
__global__ void gram16_kernel(const _Float16* __restrict__ QK, float* __restrict__ P,
                              float* __restrict__ SS) {
    const int h = blockIdx.y, s = blockIdx.x, b = blockIdx.z;
    QK += (size_t)b * OC3 * NPIX;
    const int tid = threadIdx.x;
    const int lane = tid & 63, wave = tid >> 6;
    const _Float16* q = QK + (size_t)(h * HD) * NPIX;
    const _Float16* k = QK + (size_t)(DIM + h * HD) * NPIX;
    const int rowa = lane & 15, koff = (lane >> 4) * 8;
    f32x4 acc[3][3] = {};
    float ssq[3] = {}, ssk[3] = {};
#pragma unroll
    for (int kk = 0; kk < 4; ++kk) {
        const int nk = s * 256 + wave * 128 + kk * 32 + koff;
        f16x8 aq[3], bk[3];
#pragma unroll
        for (int i = 0; i < 3; ++i)
            aq[i] = *(const f16x8*)&q[(size_t)(i * 16 + rowa) * NPIX + nk];
#pragma unroll
        for (int j = 0; j < 3; ++j)
            bk[j] = *(const f16x8*)&k[(size_t)(j * 16 + rowa) * NPIX + nk];
#pragma unroll
        for (int i = 0; i < 3; ++i)
#pragma unroll
            for (int j = 0; j < 8; ++j) {
                const float fq = (float)aq[i][j], fk = (float)bk[i][j];
                ssq[i] += fq * fq; ssk[i] += fk * fk;
            }
#pragma unroll
        for (int i = 0; i < 3; ++i)
#pragma unroll
            for (int j = 0; j < 3; ++j)
                acc[i][j] = __builtin_amdgcn_mfma_f32_16x16x32_f16(aq[i], bk[j], acc[i][j], 0, 0, 0);
    }
#pragma unroll
    for (int i = 0; i < 3; ++i) {
        ssq[i] += __shfl_xor(ssq[i], 16); ssq[i] += __shfl_xor(ssq[i], 32);
        ssk[i] += __shfl_xor(ssk[i], 16); ssk[i] += __shfl_xor(ssk[i], 32);
    }
    if (lane < 16) {
        float* ssb = SS + (((size_t)(b * HEADS + h) * NCH + s) * 2 + wave) * 96;
#pragma unroll
        for (int i = 0; i < 3; ++i) {
            ssb[i * 16 + lane]      = ssq[i];
            ssb[48 + i * 16 + lane] = ssk[i];
        }
    }
    __shared__ float red[2][HD][HD];
#pragma unroll
    for (int i = 0; i < 3; ++i)
#pragma unroll
        for (int j = 0; j < 3; ++j)
#pragma unroll
            for (int r = 0; r < 4; ++r)
                red[wave][i * 16 + (lane >> 4) * 4 + r][j * 16 + (lane & 15)] = acc[i][j][r];
    __syncthreads();
    float* pp = P + ((size_t)(b * HEADS + h) * NCH + s) * HD * HD;
    for (int idx = tid; idx < HD * HD; idx += 128)
        pp[idx] = (&red[0][0][0])[idx] + (&red[1][0][0])[idx];
}

// ---------------- reduce sumsq partials -> 1/max(||row||,eps);  rows: [b][768]
__global__ void normreduce_kernel(const float* __restrict__ SS, float* __restrict__ Fn) {
    const int idx = blockIdx.x * 256 + threadIdx.x;
    if (idx >= NB * 768) return;
    const int b = idx / 768, r = idx % 768;
    const int qk = r >= 384;
    const int h = (r - qk * 384) / HD, c = r % HD;
    const float* base = SS + ((size_t)(b * HEADS + h) * NCH) * 2 * 96 + qk * 48 + c;
    float s = 0.f;
    for (int u = 0; u < NCH * 2; ++u) s += base[u * 96];
    Fn[b * 768 + r] = 1.f / fmaxf(sqrtf(s), 1e-12f);
}

// ---------------- reduce gram partials, scale by norms+temp, softmax over d
__global__ void softmax_kernel(const float* __restrict__ P, const float* __restrict__ Fn,
                               const float* __restrict__ temp, float* __restrict__ A) {
    const int b = blockIdx.y;
    const int h = blockIdx.x / HD, c = blockIdx.x % HD;
    const float* F = Fn + b * 768;
    const float* Pb = P + (size_t)b * HEADS * NCH * HD * HD;
    const int d = threadIdx.x;
    float val = 0.f, v = -INFINITY;
    if (d < HD) {
        float sum = 0.f;
        for (int s = 0; s < NCH; ++s) sum += Pb[((size_t)(h * NCH + s) * HD + c) * HD + d];
        val = sum * F[h * HD + c] * F[DIM + h * HD + d] * temp[h];
        v = val;
    }
    float m = v;
    for (int off = 32; off; off >>= 1) m = fmaxf(m, __shfl_xor(m, off));
    const float e = (d < HD) ? expf(val - m) : 0.f;
    float se = e;
    for (int off = 32; off; off >>= 1) se += __shfl_xor(se, off);
    if (d < HD) A[((size_t)b * HEADS + h) * HD * HD + (size_t)c * HD + d] = e / se;
}

// ---------------- av + transposed f16 write: attT[b][n][384]
__global__ void av16_kernel(const float* __restrict__ At, const _Float16* __restrict__ QKdw,
                            unsigned* __restrict__ OutT) {
    const int b = blockIdx.z, h = blockIdx.y;
    At   += (size_t)b * HEADS * HD * HD;
    QKdw += (size_t)b * OC3 * NPIX;
    OutT += (size_t)b * NPIX * 192;
    __shared__ float as[HD][HD];
    __shared__ unsigned tu[512][25];
    const int tid = threadIdx.x;
    for (int i = tid; i < HD * HD; i += 256) as[i / HD][i % HD] = At[(size_t)h * HD * HD + i];
    __syncthreads();
    const int n0 = blockIdx.x * 512;
    const int n = n0 + tid * 2;
    const _Float16* v = QKdw + (size_t)(2 * DIM + h * HD) * NPIX + n;
    float acca[HD] = {}, accb[HD] = {};
    for (int d = 0; d < HD; ++d) {
        const f16x2 vv = *(const f16x2*)&v[(size_t)d * NPIX];
        const float va = (float)vv[0], vb = (float)vv[1];
#pragma unroll
        for (int c = 0; c < HD; ++c) {
            const float a = as[c][d];
            acca[c] += a * va; accb[c] += a * vb;
        }
    }
#pragma unroll
    for (int cc = 0; cc < 24; ++cc) {
        union { _Float16 hh[2]; unsigned u; } pa, pb;
        pa.hh[0] = (_Float16)acca[2 * cc]; pa.hh[1] = (_Float16)acca[2 * cc + 1];
        pb.hh[0] = (_Float16)accb[2 * cc]; pb.hh[1] = (_Float16)accb[2 * cc + 1];
        tu[tid * 2][cc] = pa.u;
        tu[tid * 2 + 1][cc] = pb.u;
    }
    __syncthreads();
#pragma unroll
    for (int i = 0; i < 48; ++i) {
        const int idx = i * 256 + tid;
        const int r = idx / 24, c = idx % 24;
        OutT[(size_t)(n0 + r) * 192 + h * 24 + c] = tu[r][c];
    }
}

extern "C" void kernel_launch(void* const* d_in, const int* in_sizes, int n_in,
                              void* d_out, int out_size, void* d_ws, size_t ws_size,
                              hipStream_t stream) {
    const float* x      = (const float*)d_in[0];
    const float* w_qkv  = (const float*)d_in[1];
    const float* w_dw   = (const float*)d_in[2];
    const float* w_proj = (const float*)d_in[3];
    const float* temp   = (const float*)d_in[4];
    float* out = (float*)d_out;

    char* ws = (char*)d_ws;
    const size_t SZ_XT   = (size_t)NB * NPIX * DIM * 2;      // 28.3 MB
    const size_t SZ_QKV  = (size_t)NB * OC3 * NPIX * 2;      // 84.9 MB
    _Float16* XT      = (_Float16*)(ws);
    _Float16* qkv16   = (_Float16*)(ws + SZ_XT);
    _Float16* qkvdw16 = (_Float16*)(ws + SZ_XT + SZ_QKV);
    _Float16* attT16  = qkv16;                                // overlays dead qkv16
    char* tail = ws + SZ_XT + 2 * SZ_QKV;
    _Float16* W16q = (_Float16*)(tail);                       // 884736 B
    _Float16* W16p = (_Float16*)(tail + 1024 * 1024);         // 294912 B
    float*    Fn   = (float*)(tail + 2 * 1024 * 1024);        // 12KB
    float*    Pp   = (float*)(tail + 2 * 1024 * 1024 + 65536);             // 10.6 MB
    float*    At   = (float*)(tail + 13 * 1024 * 1024);                    // 294912 B
    float*    SS   = (float*)(tail + 14 * 1024 * 1024);                    // 884736 B

    convert_w_kernel<<<(OC3 * DIM / 4 + 255) / 256, 256, 0, stream>>>(w_qkv, W16q, OC3 * DIM / 4);
    convert_w_kernel<<<(DIM * DIM / 4 + 255) / 256, 256, 0, stream>>>(w_proj, W16p, DIM * DIM / 4);

    convert_xt_kernel<<<dim3(NPIX / 64, DIM / 128, NB), 256, 0, stream>>>(x, XT);
    gemm16_kernel<_Float16><<<dim3(NPIX / 128, OC3 / 128, NB), 256, 0, stream>>>(
        W16q, XT, qkv16, (size_t)NPIX * DIM, (size_t)OC3 * NPIX);
    dwconv16_kernel<<<(NB * OC3 * 1152) / 256, 256, 0, stream>>>(qkv16, w_dw, qkvdw16);
    gram16_kernel<<<dim3(NCH, HEADS, NB), 128, 0, stream>>>(qkvdw16, Pp, SS);
    normreduce_kernel<<<(NB * 768 + 255) / 256, 256, 0, stream>>>(SS, Fn);
    softmax_kernel<<<dim3(HEADS * HD, NB), 64, 0, stream>>>(Pp, Fn, temp, At);
    av16_kernel<<<dim3(NPIX / 512, HEADS, NB), 256, 0, stream>>>(At, qkvdw16, (unsigned*)attT16);
    gemm16_kernel<float><<<dim3(NPIX / 128, DIM / 128, NB), 256, 0, stream>>>(
        W16p, attT16, out, (size_t)NPIX * DIM, (size_t)DIM * NPIX);
}

// Round 7
// 217.106 us; speedup vs baseline: 29.5600x; 1.0593x over previous
//
#include <hip/hip_runtime.h>
#include <hip/hip_bf16.h>
#include <math.h>

#define DIM   384
#define HEADS 8
#define HD    48
#define HH    96
#define WW    96
#define NPIX  9216
#define OC3   1152
#define NCH   36      // gram n-chunks (36*256 = 9216)
#define NB    4

typedef _Float16 f16x8 __attribute__((ext_vector_type(8)));
typedef _Float16 f16x4 __attribute__((ext_vector_type(4)));
typedef _Float16 f16x2 __attribute__((ext_vector_type(2)));
typedef float f32x4 __attribute__((ext_vector_type(4)));

// ---------------- x fp32 [b][384][NPIX] -> XT f16 [b][NPIX][384]
// 128c x 64n tiles: 256B read rows AND 256B write rows.
__global__ void convert_xt_kernel(const float* __restrict__ In, _Float16* __restrict__ Out) {
    const int b = blockIdx.z;
    In  += (size_t)b * DIM * NPIX;
    Out += (size_t)b * NPIX * DIM;
    __shared__ _Float16 t[128][66];
    const int tid = threadIdx.x;
    const int n0 = blockIdx.x * 64, c0 = blockIdx.y * 128;
    const int col = tid & 63, rb = tid >> 6;
#pragma unroll
    for (int i = 0; i < 32; ++i) {
        const int r = i * 4 + rb;   // c-local
        t[r][col] = (_Float16)In[(size_t)(c0 + r) * NPIX + n0 + col];
    }
    __syncthreads();
#pragma unroll
    for (int i = 0; i < 16; ++i) {
        const int n = i * 4 + rb;   // n-local
        f16x2 v;
        v[0] = t[col * 2][n];
        v[1] = t[col * 2 + 1][n];
        *(f16x2*)&Out[(size_t)(n0 + n) * DIM + c0 + col * 2] = v;
    }
}

// ---------------- W fp32 -> f16
__global__ void convert_w_kernel(const float* __restrict__ W, _Float16* __restrict__ O, int n4) {
    const int i = blockIdx.x * 256 + threadIdx.x;
    if (i >= n4) return;
    const float4 v = reinterpret_cast<const float4*>(W)[i];
    _Float16* o = O + (size_t)i * 4;
    o[0] = (_Float16)v.x; o[1] = (_Float16)v.y; o[2] = (_Float16)v.z; o[3] = (_Float16)v.w;
}

// ---------------- MFMA GEMM: Y[M][NPIX] = A16[M][384] * BT16[NPIX][384]^T
// 128x128 tile, BK=64, double-buffered LDS, prefetch-before-compute.
// LDS bank-conflict fix: XOR swizzle (byte ^= (row&7)<<4), applied as
// pre-swizzled GLOBAL source (linear global_load_lds dest) + swizzled ds_read.
template<typename OutT>
__global__ void gemm16_kernel(const _Float16* __restrict__ A, const _Float16* __restrict__ BT,
                              OutT* __restrict__ Y, size_t bstride, size_t ystride) {
    __shared__ _Float16 As[2][128 * 64];   // 16KB each
    __shared__ _Float16 Bs[2][128 * 64];
    const int tid = threadIdx.x;
    const int lane = tid & 63, wid = tid >> 6;
    const int m0 = blockIdx.y * 128, n0 = blockIdx.x * 128;
    BT += (size_t)blockIdx.z * bstride;
    Y  += (size_t)blockIdx.z * ystride;
    const int wrow = (wid >> 1) * 64, wcol = (wid & 1) * 64;

    auto stage = [&](int buf, int t) {
        const int k0 = t * 64;
#pragma unroll
        for (int issue = 0; issue < 4; ++issue) {
            const int p = issue * 4096 + wid * 1024 + lane * 16;   // linear LDS byte pos
            const int row = p >> 7;
            const int cb  = (p & 127) ^ ((row & 7) << 4);          // swizzled source col-bytes
            const int kp  = cb >> 1;
            __builtin_amdgcn_global_load_lds(
                (const __attribute__((address_space(1))) void*)&A[(size_t)(m0 + row) * 384 + k0 + kp],
                (__attribute__((address_space(3))) void*)((char*)&As[buf][0] + issue * 4096 + wid * 1024),
                16, 0, 0);
            __builtin_amdgcn_global_load_lds(
                (const __attribute__((address_space(1))) void*)&BT[(size_t)(n0 + row) * 384 + k0 + kp],
                (__attribute__((address_space(3))) void*)((char*)&Bs[buf][0] + issue * 4096 + wid * 1024),
                16, 0, 0);
        }
    };

    f32x4 acc[4][4] = {};
    stage(0, 0);
    __syncthreads();
    int cur = 0;
    for (int t = 0; t < 6; ++t) {
        if (t + 1 < 6) stage(cur ^ 1, t + 1);   // prefetch overlaps compute below
        const char* Ab = (const char*)&As[cur][0];
        const char* Bb = (const char*)&Bs[cur][0];
#pragma unroll
        for (int ksub = 0; ksub < 2; ++ksub) {
            const int cb = ksub * 64 + (lane >> 4) * 16;   // byte col within row
            f16x8 af[4], bf[4];
#pragma unroll
            for (int mi = 0; mi < 4; ++mi) {
                const int r = wrow + mi * 16 + (lane & 15);
                af[mi] = *(const f16x8*)(Ab + r * 128 + (cb ^ ((r & 7) << 4)));
            }
#pragma unroll
            for (int ni = 0; ni < 4; ++ni) {
                const int r = wcol + ni * 16 + (lane & 15);
                bf[ni] = *(const f16x8*)(Bb + r * 128 + (cb ^ ((r & 7) << 4)));
            }
#pragma unroll
            for (int mi = 0; mi < 4; ++mi)
#pragma unroll
                for (int ni = 0; ni < 4; ++ni)
                    acc[mi][ni] = __builtin_amdgcn_mfma_f32_16x16x32_f16(af[mi], bf[ni], acc[mi][ni], 0, 0, 0);
        }
        __syncthreads();   // drains prefetch vmcnt + protects cur swap
        cur ^= 1;
    }
#pragma unroll
    for (int mi = 0; mi < 4; ++mi)
#pragma unroll
        for (int ni = 0; ni < 4; ++ni) {
            const int gm = m0 + wrow + mi * 16 + (lane >> 4) * 4;
            const int gn = n0 + wcol + ni * 16 + (lane & 15);
#pragma unroll
            for (int r = 0; r < 4; ++r)
                Y[(size_t)(gm + r) * NPIX + gn] = (OutT)acc[mi][ni][r];
        }
}

// ---------------- depthwise 3x3 pad=1, f16 in/out, 8 px/thread
// Boundary taps come from neighbor lanes via shuffle (3 loads/thread instead of 9);
// wave-edge lanes (0/63) fall back to predicated scalar loads.
__global__ void dwconv16_kernel(const _Float16* __restrict__ In, const float* __restrict__ Wd,
                                _Float16* __restrict__ Out) {
    const int idx = blockIdx.x * 256 + threadIdx.x;   // over NB*OC3*1152
    const int lane = threadIdx.x & 63;
    const int ci = idx / 1152;                         // channel-image [0, NB*OC3)
    const int p0 = (idx - ci * 1152) * 8;              // 96%8==0 -> same image row
    const int ch = ci % OC3;
    const _Float16* ip = In + (size_t)ci * NPIX;
    const float* w = &Wd[ch * 9];
    const int y = p0 / WW, x0 = p0 % WW;
    float o[8] = {};
#pragma unroll
    for (int dy = -1; dy <= 1; ++dy) {
        const int yy = y + dy;
        if (yy < 0 || yy >= HH) continue;
        const _Float16* row = ip + yy * WW;
        const f16x8 mid = *(const f16x8*)&row[x0];
        float v[10];
#pragma unroll
        for (int j = 0; j < 8; ++j) v[j + 1] = (float)mid[j];
        // left/right neighbors from adjacent lanes (consecutive p0 within a wave)
        float left  = __shfl_up(v[8], 1);    // lane-1's mid[7] == pixel p0-1
        float right = __shfl_down(v[1], 1);  // lane+1's mid[0] == pixel p0+8
        if (lane == 0  && x0 > 0)        left  = (float)row[x0 - 1];
        if (lane == 63 && x0 + 8 < WW)   right = (float)row[x0 + 8];
        v[0] = (x0 > 0)      ? left  : 0.f;
        v[9] = (x0 + 8 < WW) ? right : 0.f;
        const float w0 = w[(dy + 1) * 3], w1 = w[(dy + 1) * 3 + 1], w2 = w[(dy + 1) * 3 + 2];
#pragma unroll
        for (int j = 0; j < 8; ++j) o[j] += w0 * v[j] + w1 * v[j + 1] + w2 * v[j + 2];
    }
    f16x8 r;
#pragma unroll
    for (int j = 0; j < 8; ++j) r[j] = (_Float16)o[j];
    *(f16x8*)&Out[(size_t)ci * NPIX + p0] = r;
}

// ---------------- MFMA gram + fused sumsq partials
// grid (NCH, HEADS, NB), block 128 = 2 waves
__global__ void gram16_kernel(const _Float16* __restrict__ QK, float* __restrict__ P,
                              float* __restrict__ SS) {
    const int h = blockIdx.y, s = blockIdx.x, b = blockIdx.z;
    QK += (size_t)b * OC3 * NPIX;
    const int tid = threadIdx.x;
    const int lane = tid & 63, wave = tid >> 6;
    const _Float16* q = QK + (size_t)(h * HD) * NPIX;
    const _Float16* k = QK + (size_t)(DIM + h * HD) * NPIX;
    const int rowa = lane & 15, koff = (lane >> 4) * 8;
    f32x4 acc[3][3] = {};
    float ssq[3] = {}, ssk[3] = {};
#pragma unroll
    for (int kk = 0; kk < 4; ++kk) {
        const int nk = s * 256 + wave * 128 + kk * 32 + koff;
        f16x8 aq[3], bk[3];
#pragma unroll
        for (int i = 0; i < 3; ++i)
            aq[i] = *(const f16x8*)&q[(size_t)(i * 16 + rowa) * NPIX + nk];
#pragma unroll
        for (int j = 0; j < 3; ++j)
            bk[j] = *(const f16x8*)&k[(size_t)(j * 16 + rowa) * NPIX + nk];
#pragma unroll
        for (int i = 0; i < 3; ++i)
#pragma unroll
            for (int j = 0; j < 8; ++j) {
                const float fq = (float)aq[i][j], fk = (float)bk[i][j];
                ssq[i] += fq * fq; ssk[i] += fk * fk;
            }
#pragma unroll
        for (int i = 0; i < 3; ++i)
#pragma unroll
            for (int j = 0; j < 3; ++j)
                acc[i][j] = __builtin_amdgcn_mfma_f32_16x16x32_f16(aq[i], bk[j], acc[i][j], 0, 0, 0);
    }
#pragma unroll
    for (int i = 0; i < 3; ++i) {
        ssq[i] += __shfl_xor(ssq[i], 16); ssq[i] += __shfl_xor(ssq[i], 32);
        ssk[i] += __shfl_xor(ssk[i], 16); ssk[i] += __shfl_xor(ssk[i], 32);
    }
    if (lane < 16) {
        float* ssb = SS + (((size_t)(b * HEADS + h) * NCH + s) * 2 + wave) * 96;
#pragma unroll
        for (int i = 0; i < 3; ++i) {
            ssb[i * 16 + lane]      = ssq[i];
            ssb[48 + i * 16 + lane] = ssk[i];
        }
    }
    __shared__ float red[2][HD][HD];
#pragma unroll
    for (int i = 0; i < 3; ++i)
#pragma unroll
        for (int j = 0; j < 3; ++j)
#pragma unroll
            for (int r = 0; r < 4; ++r)
                red[wave][i * 16 + (lane >> 4) * 4 + r][j * 16 + (lane & 15)] = acc[i][j][r];
    __syncthreads();
    float* pp = P + ((size_t)(b * HEADS + h) * NCH + s) * HD * HD;
    for (int idx = tid; idx < HD * HD; idx += 128)
        pp[idx] = (&red[0][0][0])[idx] + (&red[1][0][0])[idx];
}

// ---------------- reduce sumsq partials -> 1/max(||row||,eps);  rows: [b][768]
__global__ void normreduce_kernel(const float* __restrict__ SS, float* __restrict__ Fn) {
    const int idx = blockIdx.x * 256 + threadIdx.x;
    if (idx >= NB * 768) return;
    const int b = idx / 768, r = idx % 768;
    const int qk = r >= 384;
    const int h = (r - qk * 384) / HD, c = r % HD;
    const float* base = SS + ((size_t)(b * HEADS + h) * NCH) * 2 * 96 + qk * 48 + c;
    float s = 0.f;
    for (int u = 0; u < NCH * 2; ++u) s += base[u * 96];
    Fn[b * 768 + r] = 1.f / fmaxf(sqrtf(s), 1e-12f);
}

// ---------------- reduce gram partials, scale by norms+temp, softmax over d
__global__ void softmax_kernel(const float* __restrict__ P, const float* __restrict__ Fn,
                               const float* __restrict__ temp, float* __restrict__ A) {
    const int b = blockIdx.y;
    const int h = blockIdx.x / HD, c = blockIdx.x % HD;
    const float* F = Fn + b * 768;
    const float* Pb = P + (size_t)b * HEADS * NCH * HD * HD;
    const int d = threadIdx.x;
    float val = 0.f, v = -INFINITY;
    if (d < HD) {
        float sum = 0.f;
        for (int s = 0; s < NCH; ++s) sum += Pb[((size_t)(h * NCH + s) * HD + c) * HD + d];
        val = sum * F[h * HD + c] * F[DIM + h * HD + d] * temp[h];
        v = val;
    }
    float m = v;
    for (int off = 32; off; off >>= 1) m = fmaxf(m, __shfl_xor(m, off));
    const float e = (d < HD) ? expf(val - m) : 0.f;
    float se = e;
    for (int off = 32; off; off >>= 1) se += __shfl_xor(se, off);
    if (d < HD) A[((size_t)b * HEADS + h) * HD * HD + (size_t)c * HD + d] = e / se;
}

// ---------------- av + transposed f16 write: attT[b][n][384]
__global__ void av16_kernel(const float* __restrict__ At, const _Float16* __restrict__ QKdw,
                            unsigned* __restrict__ OutT) {
    const int b = blockIdx.z, h = blockIdx.y;
    At   += (size_t)b * HEADS * HD * HD;
    QKdw += (size_t)b * OC3 * NPIX;
    OutT += (size_t)b * NPIX * 192;
    __shared__ float as[HD][HD];
    __shared__ unsigned tu[512][25];
    const int tid = threadIdx.x;
    for (int i = tid; i < HD * HD; i += 256) as[i / HD][i % HD] = At[(size_t)h * HD * HD + i];
    __syncthreads();
    const int n0 = blockIdx.x * 512;
    const int n = n0 + tid * 2;
    const _Float16* v = QKdw + (size_t)(2 * DIM + h * HD) * NPIX + n;
    float acca[HD] = {}, accb[HD] = {};
    for (int d = 0; d < HD; ++d) {
        const f16x2 vv = *(const f16x2*)&v[(size_t)d * NPIX];
        const float va = (float)vv[0], vb = (float)vv[1];
#pragma unroll
        for (int c = 0; c < HD; ++c) {
            const float a = as[c][d];
            acca[c] += a * va; accb[c] += a * vb;
        }
    }
#pragma unroll
    for (int cc = 0; cc < 24; ++cc) {
        union { _Float16 hh[2]; unsigned u; } pa, pb;
        pa.hh[0] = (_Float16)acca[2 * cc]; pa.hh[1] = (_Float16)acca[2 * cc + 1];
        pb.hh[0] = (_Float16)accb[2 * cc]; pb.hh[1] = (_Float16)accb[2 * cc + 1];
        tu[tid * 2][cc] = pa.u;
        tu[tid * 2 + 1][cc] = pb.u;
    }
    __syncthreads();
#pragma unroll
    for (int i = 0; i < 48; ++i) {
        const int idx = i * 256 + tid;
        const int r = idx / 24, c = idx % 24;
        OutT[(size_t)(n0 + r) * 192 + h * 24 + c] = tu[r][c];
    }
}

extern "C" void kernel_launch(void* const* d_in, const int* in_sizes, int n_in,
                              void* d_out, int out_size, void* d_ws, size_t ws_size,
                              hipStream_t stream) {
    const float* x      = (const float*)d_in[0];
    const float* w_qkv  = (const float*)d_in[1];
    const float* w_dw   = (const float*)d_in[2];
    const float* w_proj = (const float*)d_in[3];
    const float* temp   = (const float*)d_in[4];
    float* out = (float*)d_out;

    char* ws = (char*)d_ws;
    const size_t SZ_XT   = (size_t)NB * NPIX * DIM * 2;      // 28.3 MB
    const size_t SZ_QKV  = (size_t)NB * OC3 * NPIX * 2;      // 84.9 MB
    _Float16* XT      = (_Float16*)(ws);
    _Float16* qkv16   = (_Float16*)(ws + SZ_XT);
    _Float16* qkvdw16 = (_Float16*)(ws + SZ_XT + SZ_QKV);
    _Float16* attT16  = qkv16;                                // overlays dead qkv16
    char* tail = ws + SZ_XT + 2 * SZ_QKV;
    _Float16* W16q = (_Float16*)(tail);                       // 884736 B
    _Float16* W16p = (_Float16*)(tail + 1024 * 1024);         // 294912 B
    float*    Fn   = (float*)(tail + 2 * 1024 * 1024);        // 12KB
    float*    Pp   = (float*)(tail + 2 * 1024 * 1024 + 65536);             // 10.6 MB
    float*    At   = (float*)(tail + 13 * 1024 * 1024);                    // 294912 B
    float*    SS   = (float*)(tail + 14 * 1024 * 1024);                    // 884736 B

    convert_w_kernel<<<(OC3 * DIM / 4 + 255) / 256, 256, 0, stream>>>(w_qkv, W16q, OC3 * DIM / 4);
    convert_w_kernel<<<(DIM * DIM / 4 + 255) / 256, 256, 0, stream>>>(w_proj, W16p, DIM * DIM / 4);

    convert_xt_kernel<<<dim3(NPIX / 64, DIM / 128, NB), 256, 0, stream>>>(x, XT);
    gemm16_kernel<_Float16><<<dim3(NPIX / 128, OC3 / 128, NB), 256, 0, stream>>>(
        W16q, XT, qkv16, (size_t)NPIX * DIM, (size_t)OC3 * NPIX);
    dwconv16_kernel<<<(NB * OC3 * 1152) / 256, 256, 0, stream>>>(qkv16, w_dw, qkvdw16);
    gram16_kernel<<<dim3(NCH, HEADS, NB), 128, 0, stream>>>(qkvdw16, Pp, SS);
    normreduce_kernel<<<(NB * 768 + 255) / 256, 256, 0, stream>>>(SS, Fn);
    softmax_kernel<<<dim3(HEADS * HD, NB), 64, 0, stream>>>(Pp, Fn, temp, At);
    av16_kernel<<<dim3(NPIX / 512, HEADS, NB), 256, 0, stream>>>(At, qkvdw16, (unsigned*)attT16);
    gemm16_kernel<float><<<dim3(NPIX / 128, DIM / 128, NB), 256, 0, stream>>>(
        W16p, attT16, out, (size_t)NPIX * DIM, (size_t)DIM * NPIX);
}

// Round 8
// 179.612 us; speedup vs baseline: 35.7306x; 1.2087x over previous
//
#include <hip/hip_runtime.h>
#include <hip/hip_bf16.h>
#include <math.h>

#define DIM   384
#define HEADS 8
#define HD    48
#define HH    96
#define WW    96
#define NPIX  9216
#define OC3   1152
#define NCH   36      // gram n-chunks (36*256 = 9216)
#define NB    4

typedef _Float16 f16x8 __attribute__((ext_vector_type(8)));
typedef _Float16 f16x4 __attribute__((ext_vector_type(4)));
typedef _Float16 f16x2 __attribute__((ext_vector_type(2)));
typedef float f32x4 __attribute__((ext_vector_type(4)));

// ---------------- x fp32 [b][384][NPIX] -> XT f16 [b][NPIX][384]
__global__ void convert_xt_kernel(const float* __restrict__ In, _Float16* __restrict__ Out) {
    const int b = blockIdx.z;
    In  += (size_t)b * DIM * NPIX;
    Out += (size_t)b * NPIX * DIM;
    __shared__ _Float16 t[128][66];
    const int tid = threadIdx.x;
    const int n0 = blockIdx.x * 64, c0 = blockIdx.y * 128;
    const int col = tid & 63, rb = tid >> 6;
#pragma unroll
    for (int i = 0; i < 32; ++i) {
        const int r = i * 4 + rb;   // c-local
        t[r][col] = (_Float16)In[(size_t)(c0 + r) * NPIX + n0 + col];
    }
    __syncthreads();
#pragma unroll
    for (int i = 0; i < 16; ++i) {
        const int n = i * 4 + rb;   // n-local
        f16x2 v;
        v[0] = t[col * 2][n];
        v[1] = t[col * 2 + 1][n];
        *(f16x2*)&Out[(size_t)(n0 + n) * DIM + c0 + col * 2] = v;
    }
}

// ---------------- v f16 [384][NPIX] -> vT f16 [b][NPIX][384]  (128c x 128n tiles)
__global__ void convert_vt_kernel(const _Float16* __restrict__ QKdw, _Float16* __restrict__ Out) {
    const int b = blockIdx.z;
    const _Float16* In = QKdw + ((size_t)b * OC3 + 2 * DIM) * NPIX;
    Out += (size_t)b * NPIX * DIM;
    __shared__ _Float16 t[128][130];
    const int tid = threadIdx.x;
    const int n0 = blockIdx.x * 128, c0 = blockIdx.y * 128;
#pragma unroll
    for (int i = 0; i < 32; ++i) {
        const int lin = i * 256 + tid;
        const int r = lin >> 6, c2 = (lin & 63) * 2;      // r: c-local row, c2: n-local col
        *(f16x2*)&t[r][c2] = *(const f16x2*)&In[(size_t)(c0 + r) * NPIX + n0 + c2];
    }
    __syncthreads();
#pragma unroll
    for (int i = 0; i < 32; ++i) {
        const int lin = i * 256 + tid;
        const int nl = lin >> 6, c2 = (lin & 63) * 2;     // nl: n-local row, c2: c-local col
        f16x2 v;
        v[0] = t[c2][nl];
        v[1] = t[c2 + 1][nl];
        *(f16x2*)&Out[(size_t)(n0 + nl) * DIM + c0 + c2] = v;
    }
}

// ---------------- W fp32 -> f16
__global__ void convert_w_kernel(const float* __restrict__ W, _Float16* __restrict__ O, int n4) {
    const int i = blockIdx.x * 256 + threadIdx.x;
    if (i >= n4) return;
    const float4 v = reinterpret_cast<const float4*>(W)[i];
    _Float16* o = O + (size_t)i * 4;
    o[0] = (_Float16)v.x; o[1] = (_Float16)v.y; o[2] = (_Float16)v.z; o[3] = (_Float16)v.w;
}

// ---------------- MFMA GEMM: Y[M][NPIX] = A16[M][384] * BT16[NPIX][384]^T
// 128x128 tile, BK=64, double-buffered LDS, prefetch-before-compute, XOR swizzle.
template<typename OutT>
__global__ void gemm16_kernel(const _Float16* __restrict__ A, const _Float16* __restrict__ BT,
                              OutT* __restrict__ Y, size_t astride, size_t bstride, size_t ystride) {
    __shared__ _Float16 As[2][128 * 64];   // 16KB each
    __shared__ _Float16 Bs[2][128 * 64];
    const int tid = threadIdx.x;
    const int lane = tid & 63, wid = tid >> 6;
    const int m0 = blockIdx.y * 128, n0 = blockIdx.x * 128;
    A  += (size_t)blockIdx.z * astride;
    BT += (size_t)blockIdx.z * bstride;
    Y  += (size_t)blockIdx.z * ystride;
    const int wrow = (wid >> 1) * 64, wcol = (wid & 1) * 64;

    auto stage = [&](int buf, int t) {
        const int k0 = t * 64;
#pragma unroll
        for (int issue = 0; issue < 4; ++issue) {
            const int p = issue * 4096 + wid * 1024 + lane * 16;   // linear LDS byte pos
            const int row = p >> 7;
            const int cb  = (p & 127) ^ ((row & 7) << 4);          // swizzled source col-bytes
            const int kp  = cb >> 1;
            __builtin_amdgcn_global_load_lds(
                (const __attribute__((address_space(1))) void*)&A[(size_t)(m0 + row) * 384 + k0 + kp],
                (__attribute__((address_space(3))) void*)((char*)&As[buf][0] + issue * 4096 + wid * 1024),
                16, 0, 0);
            __builtin_amdgcn_global_load_lds(
                (const __attribute__((address_space(1))) void*)&BT[(size_t)(n0 + row) * 384 + k0 + kp],
                (__attribute__((address_space(3))) void*)((char*)&Bs[buf][0] + issue * 4096 + wid * 1024),
                16, 0, 0);
        }
    };

    f32x4 acc[4][4] = {};
    stage(0, 0);
    __syncthreads();
    int cur = 0;
    for (int t = 0; t < 6; ++t) {
        if (t + 1 < 6) stage(cur ^ 1, t + 1);   // prefetch overlaps compute below
        const char* Ab = (const char*)&As[cur][0];
        const char* Bb = (const char*)&Bs[cur][0];
#pragma unroll
        for (int ksub = 0; ksub < 2; ++ksub) {
            const int cb = ksub * 64 + (lane >> 4) * 16;   // byte col within row
            f16x8 af[4], bf[4];
#pragma unroll
            for (int mi = 0; mi < 4; ++mi) {
                const int r = wrow + mi * 16 + (lane & 15);
                af[mi] = *(const f16x8*)(Ab + r * 128 + (cb ^ ((r & 7) << 4)));
            }
#pragma unroll
            for (int ni = 0; ni < 4; ++ni) {
                const int r = wcol + ni * 16 + (lane & 15);
                bf[ni] = *(const f16x8*)(Bb + r * 128 + (cb ^ ((r & 7) << 4)));
            }
#pragma unroll
            for (int mi = 0; mi < 4; ++mi)
#pragma unroll
                for (int ni = 0; ni < 4; ++ni)
                    acc[mi][ni] = __builtin_amdgcn_mfma_f32_16x16x32_f16(af[mi], bf[ni], acc[mi][ni], 0, 0, 0);
        }
        __syncthreads();
        cur ^= 1;
    }
#pragma unroll
    for (int mi = 0; mi < 4; ++mi)
#pragma unroll
        for (int ni = 0; ni < 4; ++ni) {
            const int gm = m0 + wrow + mi * 16 + (lane >> 4) * 4;
            const int gn = n0 + wcol + ni * 16 + (lane & 15);
#pragma unroll
            for (int r = 0; r < 4; ++r)
                Y[(size_t)(gm + r) * NPIX + gn] = (OutT)acc[mi][ni][r];
        }
}

// ---------------- depthwise 3x3 pad=1, f16 in/out, 8 px/thread, shuffle boundaries
__global__ void dwconv16_kernel(const _Float16* __restrict__ In, const float* __restrict__ Wd,
                                _Float16* __restrict__ Out) {
    const int idx = blockIdx.x * 256 + threadIdx.x;   // over NB*OC3*1152
    const int lane = threadIdx.x & 63;
    const int ci = idx / 1152;                         // channel-image [0, NB*OC3)
    const int p0 = (idx - ci * 1152) * 8;
    const int ch = ci % OC3;
    const _Float16* ip = In + (size_t)ci * NPIX;
    const float* w = &Wd[ch * 9];
    const int y = p0 / WW, x0 = p0 % WW;
    float o[8] = {};
#pragma unroll
    for (int dy = -1; dy <= 1; ++dy) {
        const int yy = y + dy;
        if (yy < 0 || yy >= HH) continue;
        const _Float16* row = ip + yy * WW;
        const f16x8 mid = *(const f16x8*)&row[x0];
        float v[10];
#pragma unroll
        for (int j = 0; j < 8; ++j) v[j + 1] = (float)mid[j];
        float left  = __shfl_up(v[8], 1);
        float right = __shfl_down(v[1], 1);
        if (lane == 0  && x0 > 0)        left  = (float)row[x0 - 1];
        if (lane == 63 && x0 + 8 < WW)   right = (float)row[x0 + 8];
        v[0] = (x0 > 0)      ? left  : 0.f;
        v[9] = (x0 + 8 < WW) ? right : 0.f;
        const float w0 = w[(dy + 1) * 3], w1 = w[(dy + 1) * 3 + 1], w2 = w[(dy + 1) * 3 + 2];
#pragma unroll
        for (int j = 0; j < 8; ++j) o[j] += w0 * v[j] + w1 * v[j + 1] + w2 * v[j + 2];
    }
    f16x8 r;
#pragma unroll
    for (int j = 0; j < 8; ++j) r[j] = (_Float16)o[j];
    *(f16x8*)&Out[(size_t)ci * NPIX + p0] = r;
}

// ---------------- MFMA gram + fused sumsq partials
__global__ void gram16_kernel(const _Float16* __restrict__ QK, float* __restrict__ P,
                              float* __restrict__ SS) {
    const int h = blockIdx.y, s = blockIdx.x, b = blockIdx.z;
    QK += (size_t)b * OC3 * NPIX;
    const int tid = threadIdx.x;
    const int lane = tid & 63, wave = tid >> 6;
    const _Float16* q = QK + (size_t)(h * HD) * NPIX;
    const _Float16* k = QK + (size_t)(DIM + h * HD) * NPIX;
    const int rowa = lane & 15, koff = (lane >> 4) * 8;
    f32x4 acc[3][3] = {};
    float ssq[3] = {}, ssk[3] = {};
#pragma unroll
    for (int kk = 0; kk < 4; ++kk) {
        const int nk = s * 256 + wave * 128 + kk * 32 + koff;
        f16x8 aq[3], bk[3];
#pragma unroll
        for (int i = 0; i < 3; ++i)
            aq[i] = *(const f16x8*)&q[(size_t)(i * 16 + rowa) * NPIX + nk];
#pragma unroll
        for (int j = 0; j < 3; ++j)
            bk[j] = *(const f16x8*)&k[(size_t)(j * 16 + rowa) * NPIX + nk];
#pragma unroll
        for (int i = 0; i < 3; ++i)
#pragma unroll
            for (int j = 0; j < 8; ++j) {
                const float fq = (float)aq[i][j], fk = (float)bk[i][j];
                ssq[i] += fq * fq; ssk[i] += fk * fk;
            }
#pragma unroll
        for (int i = 0; i < 3; ++i)
#pragma unroll
            for (int j = 0; j < 3; ++j)
                acc[i][j] = __builtin_amdgcn_mfma_f32_16x16x32_f16(aq[i], bk[j], acc[i][j], 0, 0, 0);
    }
#pragma unroll
    for (int i = 0; i < 3; ++i) {
        ssq[i] += __shfl_xor(ssq[i], 16); ssq[i] += __shfl_xor(ssq[i], 32);
        ssk[i] += __shfl_xor(ssk[i], 16); ssk[i] += __shfl_xor(ssk[i], 32);
    }
    if (lane < 16) {
        float* ssb = SS + (((size_t)(b * HEADS + h) * NCH + s) * 2 + wave) * 96;
#pragma unroll
        for (int i = 0; i < 3; ++i) {
            ssb[i * 16 + lane]      = ssq[i];
            ssb[48 + i * 16 + lane] = ssk[i];
        }
    }
    __shared__ float red[2][HD][HD];
#pragma unroll
    for (int i = 0; i < 3; ++i)
#pragma unroll
        for (int j = 0; j < 3; ++j)
#pragma unroll
            for (int r = 0; r < 4; ++r)
                red[wave][i * 16 + (lane >> 4) * 4 + r][j * 16 + (lane & 15)] = acc[i][j][r];
    __syncthreads();
    float* pp = P + ((size_t)(b * HEADS + h) * NCH + s) * HD * HD;
    for (int idx = tid; idx < HD * HD; idx += 128)
        pp[idx] = (&red[0][0][0])[idx] + (&red[1][0][0])[idx];
}

// ---------------- reduce sumsq partials -> 1/max(||row||,eps)
__global__ void normreduce_kernel(const float* __restrict__ SS, float* __restrict__ Fn) {
    const int idx = blockIdx.x * 256 + threadIdx.x;
    if (idx >= NB * 768) return;
    const int b = idx / 768, r = idx % 768;
    const int qk = r >= 384;
    const int h = (r - qk * 384) / HD, c = r % HD;
    const float* base = SS + ((size_t)(b * HEADS + h) * NCH) * 2 * 96 + qk * 48 + c;
    float s = 0.f;
    for (int u = 0; u < NCH * 2; ++u) s += base[u * 96];
    Fn[b * 768 + r] = 1.f / fmaxf(sqrtf(s), 1e-12f);
}

// ---------------- reduce gram partials, scale by norms+temp, softmax over d
__global__ void softmax_kernel(const float* __restrict__ P, const float* __restrict__ Fn,
                               const float* __restrict__ temp, float* __restrict__ A) {
    const int b = blockIdx.y;
    const int h = blockIdx.x / HD, c = blockIdx.x % HD;
    const float* F = Fn + b * 768;
    const float* Pb = P + (size_t)b * HEADS * NCH * HD * HD;
    const int d = threadIdx.x;
    float val = 0.f, v = -INFINITY;
    if (d < HD) {
        float sum = 0.f;
        for (int s = 0; s < NCH; ++s) sum += Pb[((size_t)(h * NCH + s) * HD + c) * HD + d];
        val = sum * F[h * HD + c] * F[DIM + h * HD + d] * temp[h];
        v = val;
    }
    float m = v;
    for (int off = 32; off; off >>= 1) m = fmaxf(m, __shfl_xor(m, off));
    const float e = (d < HD) ? expf(val - m) : 0.f;
    float se = e;
    for (int off = 32; off; off >>= 1) se += __shfl_xor(se, off);
    if (d < HD) A[((size_t)b * HEADS + h) * HD * HD + (size_t)c * HD + d] = e / se;
}

// ---------------- WP_eff[b][o][h*48+d] = sum_c wp[o][h*48+c] * attn[b][h][c][d]
// grid (8 og, HEADS, NB), block 256. All operands staged in LDS.
__global__ void wpeff_kernel(const float* __restrict__ Wp, const float* __restrict__ At,
                             _Float16* __restrict__ WPe) {
    const int og = blockIdx.x, h = blockIdx.y, b = blockIdx.z;
    const int o0 = og * 48;
    const int tid = threadIdx.x;
    __shared__ float as2[HD][HD];   // attn[c][d]
    __shared__ float wpb[HD][HD];   // wp[o0+r][h*48+c]
    const float* ab = At + ((size_t)(b * HEADS + h)) * HD * HD;
    for (int wi = tid; wi < HD * HD; wi += 256) {
        (&as2[0][0])[wi] = ab[wi];
        wpb[wi / HD][wi % HD] = Wp[(size_t)(o0 + wi / HD) * DIM + h * HD + wi % HD];
    }
    __syncthreads();
#pragma unroll
    for (int it = 0; it < 3; ++it) {
        const int wi = it * 256 + tid;       // 48o * 12 d-quads = 576
        if (wi >= 576) break;
        const int ol = wi / 12, d0 = (wi % 12) * 4;
        f32x4 acc = {};
#pragma unroll
        for (int c = 0; c < HD; ++c) {
            const float wv = wpb[ol][c];
            const f32x4 a4 = *(const f32x4*)&as2[c][d0];
            acc.x += wv * a4.x; acc.y += wv * a4.y; acc.z += wv * a4.z; acc.w += wv * a4.w;
        }
        f16x4 r;
        r[0] = (_Float16)acc.x; r[1] = (_Float16)acc.y;
        r[2] = (_Float16)acc.z; r[3] = (_Float16)acc.w;
        *(f16x4*)&WPe[((size_t)b * DIM + o0 + ol) * DIM + h * HD + d0] = r;
    }
}

extern "C" void kernel_launch(void* const* d_in, const int* in_sizes, int n_in,
                              void* d_out, int out_size, void* d_ws, size_t ws_size,
                              hipStream_t stream) {
    const float* x      = (const float*)d_in[0];
    const float* w_qkv  = (const float*)d_in[1];
    const float* w_dw   = (const float*)d_in[2];
    const float* w_proj = (const float*)d_in[3];
    const float* temp   = (const float*)d_in[4];
    float* out = (float*)d_out;

    char* ws = (char*)d_ws;
    const size_t SZ_XT   = (size_t)NB * NPIX * DIM * 2;      // 28.3 MB
    const size_t SZ_QKV  = (size_t)NB * OC3 * NPIX * 2;      // 84.9 MB
    _Float16* XT      = (_Float16*)(ws);
    _Float16* qkv16   = (_Float16*)(ws + SZ_XT);
    _Float16* qkvdw16 = (_Float16*)(ws + SZ_XT + SZ_QKV);
    _Float16* vT16    = qkv16;                                // overlays dead qkv16
    char* tail = ws + SZ_XT + 2 * SZ_QKV;
    _Float16* W16q = (_Float16*)(tail);                       // 884736 B
    float*    Fn   = (float*)(tail + 2 * 1024 * 1024);        // 12KB
    float*    Pp   = (float*)(tail + 2 * 1024 * 1024 + 65536);             // 10.6 MB
    float*    At   = (float*)(tail + 13 * 1024 * 1024);                    // 294912 B
    float*    SS   = (float*)(tail + 14 * 1024 * 1024);                    // 884736 B
    _Float16* WPe  = (_Float16*)(tail + 15 * 1024 * 1024);                 // 1.18 MB

    convert_w_kernel<<<(OC3 * DIM / 4 + 255) / 256, 256, 0, stream>>>(w_qkv, W16q, OC3 * DIM / 4);

    convert_xt_kernel<<<dim3(NPIX / 64, DIM / 128, NB), 256, 0, stream>>>(x, XT);
    gemm16_kernel<_Float16><<<dim3(NPIX / 128, OC3 / 128, NB), 256, 0, stream>>>(
        W16q, XT, qkv16, 0, (size_t)NPIX * DIM, (size_t)OC3 * NPIX);
    dwconv16_kernel<<<(NB * OC3 * 1152) / 256, 256, 0, stream>>>(qkv16, w_dw, qkvdw16);
    gram16_kernel<<<dim3(NCH, HEADS, NB), 128, 0, stream>>>(qkvdw16, Pp, SS);
    normreduce_kernel<<<(NB * 768 + 255) / 256, 256, 0, stream>>>(SS, Fn);
    softmax_kernel<<<dim3(HEADS * HD, NB), 64, 0, stream>>>(Pp, Fn, temp, At);
    convert_vt_kernel<<<dim3(NPIX / 128, DIM / 128, NB), 256, 0, stream>>>(qkvdw16, vT16);
    wpeff_kernel<<<dim3(8, HEADS, NB), 256, 0, stream>>>(w_proj, At, WPe);
    gemm16_kernel<float><<<dim3(NPIX / 128, DIM / 128, NB), 256, 0, stream>>>(
        WPe, vT16, out, (size_t)DIM * DIM, (size_t)NPIX * DIM, (size_t)DIM * NPIX);
}